// Round 6
// baseline (298.967 us; speedup 1.0000x reference)
//
#include <hip/hip_runtime.h>

#define NN 100000
#define IND 64
#define HID 128
#define NE 1600000

// ---- CSR build v3: fixed-capacity 256-node buckets ----
#define BKT2 256
#define NBKT2 ((NN + BKT2 - 1) / BKT2)     // 391 buckets
#define CAP 4992                           // mean 4092 + ~14 sigma
#define EPB 4096
#define NBLK_E ((NE + EPB - 1) / EPB)      // 391 edge chunks

// ---- fallback fp32 CSR path ----
#define SCAN_CHUNK 1024
#define NSB ((NN + SCAN_CHUNK - 1) / SCAN_CHUNK)

typedef __attribute__((ext_vector_type(8))) short bf16x8;
typedef __attribute__((ext_vector_type(4))) float f32x4;
typedef __attribute__((ext_vector_type(2))) float f32x2;

static __device__ __forceinline__ unsigned short f2bf(float f) {
    unsigned u = __float_as_uint(f);
    u = (u + 0x7FFFu + ((u >> 16) & 1u)) >> 16;   // RNE
    return (unsigned short)u;
}
static __device__ __forceinline__ unsigned pack2(float a, float b) {
    return (unsigned)f2bf(a) | ((unsigned)f2bf(b) << 16);
}

// ===================== CSR build v3 =====================

__global__ __launch_bounds__(512) void zero_small_kernel(int* __restrict__ p, int n) {
    int i = threadIdx.x;
    if (i < n) p[i] = 0;
}

__global__ __launch_bounds__(512) void binA_kernel(const int* __restrict__ src,
                                                   const int* __restrict__ dst,
                                                   int* __restrict__ bktcur,
                                                   unsigned* __restrict__ bins) {
    __shared__ int hcnt[NBKT2];
    __shared__ int rbase[NBKT2];
    int t = threadIdx.x;
    int e0 = blockIdx.x * EPB;
    int ce = min(EPB, NE - e0);
    for (int i = t; i < NBKT2; i += 512) hcnt[i] = 0;
    __syncthreads();
    for (int i = t; i < ce; i += 512)
        atomicAdd(&hcnt[dst[e0 + i] >> 8], 1);
    __syncthreads();
    for (int i = t; i < NBKT2; i += 512) {
        int c = hcnt[i];
        rbase[i] = c ? atomicAdd(&bktcur[i], c) : 0;
        hcnt[i] = 0;
    }
    __syncthreads();
    for (int i = t; i < ce; i += 512) {
        int d = dst[e0 + i];
        int b = d >> 8;
        int r = atomicAdd(&hcnt[b], 1);
        bins[(size_t)b * CAP + rbase[b] + r] =
            (unsigned)src[e0 + i] | ((unsigned)(d & 255) << 17);
    }
}

__global__ __launch_bounds__(256) void binB_kernel(const int* __restrict__ bktcur,
                                                   unsigned* __restrict__ bins,
                                                   int* __restrict__ cnt,
                                                   int* __restrict__ off) {
    __shared__ unsigned ebuf[CAP];
    __shared__ int ncnt[BKT2];
    __shared__ int nofs[BKT2];
    __shared__ int wtot[4];
    int t = threadIdx.x, lane = t & 63, w = t >> 6;
    int b = blockIdx.x;
    int m = bktcur[b];
    size_t base = (size_t)b * CAP;
    for (int i = t; i < m; i += 256) ebuf[i] = bins[base + i];
    ncnt[t] = 0;
    __syncthreads();
    for (int i = t; i < m; i += 256)
        atomicAdd(&ncnt[ebuf[i] >> 17], 1);
    __syncthreads();
    int v = ncnt[t];
    int incl = v;
    #pragma unroll
    for (int o = 1; o < 64; o <<= 1) {
        int u = __shfl_up(incl, o);
        if (lane >= o) incl += u;
    }
    if (lane == 63) wtot[w] = incl;
    __syncthreads();
    int wbase = 0;
    #pragma unroll
    for (int i = 0; i < 4; ++i) if (i < w) wbase += wtot[i];
    int ex = wbase + incl - v;
    nofs[t] = ex;
    int node = b * BKT2 + t;
    if (node < NN) { cnt[node] = v; off[node] = (int)base + ex; }
    __syncthreads();
    for (int i = t; i < m; i += 256) {
        unsigned val = ebuf[i];
        int r = atomicAdd(&nofs[val >> 17], 1);
        bins[base + r] = val & 0x1FFFFu;
    }
}

// ===================== conversions / packing =====================

__global__ __launch_bounds__(256) void cvt_xq_kernel(const float4* __restrict__ x,
                                                     unsigned* __restrict__ xq) {
    int i = blockIdx.x * 256 + threadIdx.x;   // over NN*IND/4 exact
    float4 v = x[i];
    int u = __builtin_amdgcn_cvt_pk_fp8_f32(v.x, v.y, 0, false);
    u = __builtin_amdgcn_cvt_pk_fp8_f32(v.z, v.w, u, true);
    xq[i] = (unsigned)u;
}

// pack Wcat = [Wr(k<Khalf) ; Wl] into MFMA B-fragment order
__global__ __launch_bounds__(256) void packW_kernel(const float* __restrict__ Wr,
                                                    const float* __restrict__ Wl,
                                                    int Khalf, int KS,
                                                    unsigned short* __restrict__ Wp) {
    int t = blockIdx.x * 256 + threadIdx.x;
    if (t >= 8 * KS * 64) return;
    int l  = t & 63;
    int ks = (t >> 6) % KS;
    int jt = t / (64 * KS);
    int j  = jt * 16 + (l & 15);
    int kb = ks * 32 + (l >> 4) * 8;
    unsigned short v[8];
    #pragma unroll
    for (int i = 0; i < 8; ++i) {
        int k = kb + i;
        float w = (k < Khalf) ? Wr[k * HID + j] : Wl[(k - Khalf) * HID + j];
        v[i] = f2bf(w);
    }
    ushort4 lo, hi;
    lo.x = v[0]; lo.y = v[1]; lo.z = v[2]; lo.w = v[3];
    hi.x = v[4]; hi.y = v[5]; hi.z = v[6]; hi.w = v[7];
    ushort4* d = reinterpret_cast<ushort4*>(Wp + (size_t)t * 8);
    d[0] = lo; d[1] = hi;
}

// ===================== fused layer 1: agg(x_fp8) + MFMA =====================
// block = 64 nodes, 4 waves; wave w owns rows w*16..w*16+15

__global__ __launch_bounds__(256) void fused1_kernel(const float* __restrict__ x,
                                                     const unsigned char* __restrict__ xq,
                                                     const int* __restrict__ srcs,
                                                     const int* __restrict__ off,
                                                     const int* __restrict__ cnt,
                                                     const unsigned short* __restrict__ Wp,
                                                     const float* __restrict__ b,
                                                     float* __restrict__ h1f,
                                                     unsigned char* __restrict__ h1q) {
    __shared__ unsigned short m1[64][IND + 8];   // +8 pad -> 2-way max aliasing
    int t = threadIdx.x, w = t >> 6, l = t & 63;
    int blk = blockIdx.x;
    // ---- phase 1: per-wave aggregation of 16 node means ----
    {
        int ep = l >> 4, d4 = (l & 15) * 4;
        for (int nn = 0; nn < 16; ++nn) {
            int lr = w * 16 + nn;
            int n = blk * 64 + lr;
            int deg = (n < NN) ? cnt[n] : 0;
            int s0 = (n < NN) ? off[n] : 0;
            float a0 = 0.f, a1 = 0.f, a2 = 0.f, a3 = 0.f;
            int e = ep;
            for (; e + 4 < deg; e += 8) {
                int sA = srcs[s0 + e], sB = srcs[s0 + e + 4];
                unsigned uA = *reinterpret_cast<const unsigned*>(xq + (size_t)sA * IND + d4);
                unsigned uB = *reinterpret_cast<const unsigned*>(xq + (size_t)sB * IND + d4);
                f32x2 lA = __builtin_amdgcn_cvt_pk_f32_fp8((int)uA, false);
                f32x2 hA = __builtin_amdgcn_cvt_pk_f32_fp8((int)uA, true);
                f32x2 lB = __builtin_amdgcn_cvt_pk_f32_fp8((int)uB, false);
                f32x2 hB = __builtin_amdgcn_cvt_pk_f32_fp8((int)uB, true);
                a0 += lA.x + lB.x; a1 += lA.y + lB.y;
                a2 += hA.x + hB.x; a3 += hA.y + hB.y;
            }
            for (; e < deg; e += 4) {
                int s = srcs[s0 + e];
                unsigned u = *reinterpret_cast<const unsigned*>(xq + (size_t)s * IND + d4);
                f32x2 lo = __builtin_amdgcn_cvt_pk_f32_fp8((int)u, false);
                f32x2 hi = __builtin_amdgcn_cvt_pk_f32_fp8((int)u, true);
                a0 += lo.x; a1 += lo.y; a2 += hi.x; a3 += hi.y;
            }
            a0 += __shfl_down(a0, 32); a1 += __shfl_down(a1, 32);
            a2 += __shfl_down(a2, 32); a3 += __shfl_down(a3, 32);
            a0 += __shfl_down(a0, 16); a1 += __shfl_down(a1, 16);
            a2 += __shfl_down(a2, 16); a3 += __shfl_down(a3, 16);
            if (l < 16) {
                float inv = 1.f / fmaxf((float)deg, 1.f);
                uint2 o;
                o.x = pack2(a0 * inv, a1 * inv);
                o.y = pack2(a2 * inv, a3 * inv);
                *reinterpret_cast<uint2*>(&m1[lr][d4]) = o;
            }
        }
    }
    __syncthreads();
    // ---- phase 2: MFMA [x | m1] @ Wp + b, relu ----
    int row0 = blk * 64 + w * 16;
    int arow = row0 + (l & 15); if (arow > NN - 1) arow = NN - 1;
    int kcol = (l >> 4) * 8;
    f32x4 acc[8];
    #pragma unroll
    for (int jt = 0; jt < 8; ++jt) { acc[jt][0] = 0.f; acc[jt][1] = 0.f; acc[jt][2] = 0.f; acc[jt][3] = 0.f; }
    #pragma unroll
    for (int ks = 0; ks < 4; ++ks) {
        bf16x8 a;
        int c = (ks & 1) * 32 + kcol;
        if (ks < 2) {
            const float* xr = x + (size_t)arow * IND + c;
            float4 f0 = *reinterpret_cast<const float4*>(xr);
            float4 f1 = *reinterpret_cast<const float4*>(xr + 4);
            a[0] = (short)f2bf(f0.x); a[1] = (short)f2bf(f0.y);
            a[2] = (short)f2bf(f0.z); a[3] = (short)f2bf(f0.w);
            a[4] = (short)f2bf(f1.x); a[5] = (short)f2bf(f1.y);
            a[6] = (short)f2bf(f1.z); a[7] = (short)f2bf(f1.w);
        } else {
            a = *reinterpret_cast<const bf16x8*>(&m1[w * 16 + (l & 15)][c]);
        }
        #pragma unroll
        for (int jt = 0; jt < 8; ++jt) {
            bf16x8 bb = *reinterpret_cast<const bf16x8*>(Wp + ((size_t)(jt * 4 + ks) * 64 + l) * 8);
            acc[jt] = __builtin_amdgcn_mfma_f32_16x16x32_bf16(a, bb, acc[jt], 0, 0, 0);
        }
    }
    int rbase = row0 + (l >> 4) * 4;
    #pragma unroll
    for (int jt = 0; jt < 8; ++jt) {
        int col = jt * 16 + (l & 15);
        float bias = b[col];
        #pragma unroll
        for (int r = 0; r < 4; ++r) {
            int row = rbase + r;
            if (row < NN) {
                float v = fmaxf(acc[jt][r] + bias, 0.f);
                h1f[(size_t)row * HID + col] = v;
                unsigned q8 = (unsigned)__builtin_amdgcn_cvt_pk_fp8_f32(v, 0.f, 0, false) & 0xFFu;
                h1q[(size_t)row * HID + col] = (unsigned char)q8;
            }
        }
    }
}

// ===================== fused layer 2: agg(h1_fp8) + MFMA + head =====================

__global__ __launch_bounds__(256) void fused2_kernel(const float* __restrict__ h1f,
                                                     const unsigned char* __restrict__ h1q,
                                                     const int* __restrict__ srcs,
                                                     const int* __restrict__ off,
                                                     const int* __restrict__ cnt,
                                                     const unsigned short* __restrict__ Wp,
                                                     const float* __restrict__ b,
                                                     const float* __restrict__ Wout,
                                                     const float* __restrict__ bout,
                                                     float* __restrict__ h2f,
                                                     float* __restrict__ out) {
    __shared__ unsigned short m2[64][HID + 8];   // +8 pad
    int t = threadIdx.x, w = t >> 6, l = t & 63;
    int blk = blockIdx.x;
    // ---- phase 1: per-wave aggregation of 16 node means ----
    {
        int ep = l >> 5, d4 = (l & 31) * 4;
        for (int nn = 0; nn < 16; ++nn) {
            int lr = w * 16 + nn;
            int n = blk * 64 + lr;
            int deg = (n < NN) ? cnt[n] : 0;
            int s0 = (n < NN) ? off[n] : 0;
            float a0 = 0.f, a1 = 0.f, a2 = 0.f, a3 = 0.f;
            int e = ep;
            for (; e + 6 < deg; e += 8) {
                int sA = srcs[s0 + e],     sB = srcs[s0 + e + 2];
                int sC = srcs[s0 + e + 4], sD = srcs[s0 + e + 6];
                unsigned uA = *reinterpret_cast<const unsigned*>(h1q + (size_t)sA * HID + d4);
                unsigned uB = *reinterpret_cast<const unsigned*>(h1q + (size_t)sB * HID + d4);
                unsigned uC = *reinterpret_cast<const unsigned*>(h1q + (size_t)sC * HID + d4);
                unsigned uD = *reinterpret_cast<const unsigned*>(h1q + (size_t)sD * HID + d4);
                f32x2 lA = __builtin_amdgcn_cvt_pk_f32_fp8((int)uA, false);
                f32x2 hA = __builtin_amdgcn_cvt_pk_f32_fp8((int)uA, true);
                f32x2 lB = __builtin_amdgcn_cvt_pk_f32_fp8((int)uB, false);
                f32x2 hB = __builtin_amdgcn_cvt_pk_f32_fp8((int)uB, true);
                f32x2 lC = __builtin_amdgcn_cvt_pk_f32_fp8((int)uC, false);
                f32x2 hC = __builtin_amdgcn_cvt_pk_f32_fp8((int)uC, true);
                f32x2 lD = __builtin_amdgcn_cvt_pk_f32_fp8((int)uD, false);
                f32x2 hD = __builtin_amdgcn_cvt_pk_f32_fp8((int)uD, true);
                a0 += (lA.x + lB.x) + (lC.x + lD.x);
                a1 += (lA.y + lB.y) + (lC.y + lD.y);
                a2 += (hA.x + hB.x) + (hC.x + hD.x);
                a3 += (hA.y + hB.y) + (hC.y + hD.y);
            }
            for (; e < deg; e += 2) {
                int s = srcs[s0 + e];
                unsigned u = *reinterpret_cast<const unsigned*>(h1q + (size_t)s * HID + d4);
                f32x2 lo = __builtin_amdgcn_cvt_pk_f32_fp8((int)u, false);
                f32x2 hi = __builtin_amdgcn_cvt_pk_f32_fp8((int)u, true);
                a0 += lo.x; a1 += lo.y; a2 += hi.x; a3 += hi.y;
            }
            a0 += __shfl_down(a0, 32); a1 += __shfl_down(a1, 32);
            a2 += __shfl_down(a2, 32); a3 += __shfl_down(a3, 32);
            if (l < 32) {
                float inv = 1.f / fmaxf((float)deg, 1.f);
                uint2 o;
                o.x = pack2(a0 * inv, a1 * inv);
                o.y = pack2(a2 * inv, a3 * inv);
                *reinterpret_cast<uint2*>(&m2[lr][d4]) = o;
            }
        }
    }
    __syncthreads();
    // ---- phase 2: MFMA [h1 | m2] @ Wp + b, + fused head ----
    int row0 = blk * 64 + w * 16;
    int arow = row0 + (l & 15); if (arow > NN - 1) arow = NN - 1;
    int kcol = (l >> 4) * 8;
    f32x4 acc[8];
    #pragma unroll
    for (int jt = 0; jt < 8; ++jt) { acc[jt][0] = 0.f; acc[jt][1] = 0.f; acc[jt][2] = 0.f; acc[jt][3] = 0.f; }
    #pragma unroll
    for (int ks = 0; ks < 8; ++ks) {
        bf16x8 a;
        int c = (ks & 3) * 32 + kcol;
        if (ks < 4) {
            const float* hr = h1f + (size_t)arow * HID + c;
            float4 f0 = *reinterpret_cast<const float4*>(hr);
            float4 f1 = *reinterpret_cast<const float4*>(hr + 4);
            a[0] = (short)f2bf(f0.x); a[1] = (short)f2bf(f0.y);
            a[2] = (short)f2bf(f0.z); a[3] = (short)f2bf(f0.w);
            a[4] = (short)f2bf(f1.x); a[5] = (short)f2bf(f1.y);
            a[6] = (short)f2bf(f1.z); a[7] = (short)f2bf(f1.w);
        } else {
            a = *reinterpret_cast<const bf16x8*>(&m2[w * 16 + (l & 15)][c]);
        }
        #pragma unroll
        for (int jt = 0; jt < 8; ++jt) {
            bf16x8 bb = *reinterpret_cast<const bf16x8*>(Wp + ((size_t)(jt * 8 + ks) * 64 + l) * 8);
            acc[jt] = __builtin_amdgcn_mfma_f32_16x16x32_bf16(a, bb, acc[jt], 0, 0, 0);
        }
    }
    int rbase = row0 + (l >> 4) * 4;
    float hs0 = 0.f, hs1 = 0.f, hs2 = 0.f, hs3 = 0.f;
    #pragma unroll
    for (int jt = 0; jt < 8; ++jt) {
        int col = jt * 16 + (l & 15);
        float bias = b[col];
        float wo = Wout[col];
        #pragma unroll
        for (int r = 0; r < 4; ++r) {
            int row = rbase + r;
            float v = acc[jt][r] + bias;
            if (row < NN) h2f[(size_t)row * HID + col] = v;
            if (r == 0) hs0 += v * wo;
            else if (r == 1) hs1 += v * wo;
            else if (r == 2) hs2 += v * wo;
            else hs3 += v * wo;
        }
    }
    #pragma unroll
    for (int o = 1; o < 16; o <<= 1) {
        hs0 += __shfl_xor(hs0, o);
        hs1 += __shfl_xor(hs1, o);
        hs2 += __shfl_xor(hs2, o);
        hs3 += __shfl_xor(hs3, o);
    }
    if ((l & 15) == 0) {
        float bo = bout[0];
        if (rbase + 0 < NN) out[rbase + 0] = hs0 + bo;
        if (rbase + 1 < NN) out[rbase + 1] = hs1 + bo;
        if (rbase + 2 < NN) out[rbase + 2] = hs2 + bo;
        if (rbase + 3 < NN) out[rbase + 3] = hs3 + bo;
    }
}

// ===================== fp32 CSR fallback (round-2) =====================

__global__ __launch_bounds__(256) void zero_int_kernel(int4* __restrict__ p, int n4) {
    int i = blockIdx.x * 256 + threadIdx.x;
    if (i < n4) p[i] = make_int4(0, 0, 0, 0);
}

__global__ __launch_bounds__(256) void hist_kernel(const int* __restrict__ dst,
                                                   int* __restrict__ cnt) {
    int e = blockIdx.x * 256 + threadIdx.x;
    if (e < NE) atomicAdd(&cnt[dst[e]], 1);
}

__global__ __launch_bounds__(256) void scanA_kernel(const int* __restrict__ cnt,
                                                    int* __restrict__ bsums) {
    int b = blockIdx.x, t = threadIdx.x;
    int base = b * SCAN_CHUNK + t * 4;
    int s = 0;
    #pragma unroll
    for (int k = 0; k < 4; ++k) { int i = base + k; if (i < NN) s += cnt[i]; }
    #pragma unroll
    for (int o = 32; o > 0; o >>= 1) s += __shfl_down(s, o);
    __shared__ int wsum[4];
    if ((t & 63) == 0) wsum[t >> 6] = s;
    __syncthreads();
    if (t == 0) bsums[b] = wsum[0] + wsum[1] + wsum[2] + wsum[3];
}

__global__ void scanB_kernel(int* __restrict__ bsums) {
    int acc = 0;
    for (int i = 0; i < NSB; ++i) { int v = bsums[i]; bsums[i] = acc; acc += v; }
}

__global__ __launch_bounds__(256) void scanC_kernel(const int* __restrict__ cnt,
                                                    const int* __restrict__ bsums,
                                                    int* __restrict__ off,
                                                    int* __restrict__ cur) {
    int b = blockIdx.x, t = threadIdx.x;
    int lane = t & 63, w = t >> 6;
    int base = b * SCAN_CHUNK + t * 4;
    int v[4]; int s = 0;
    #pragma unroll
    for (int k = 0; k < 4; ++k) {
        int i = base + k;
        v[k] = (i < NN) ? cnt[i] : 0;
        s += v[k];
    }
    int inc = s;
    #pragma unroll
    for (int o = 1; o < 64; o <<= 1) {
        int xv = __shfl_up(inc, o);
        if (lane >= o) inc += xv;
    }
    __shared__ int wsum[4];
    if (lane == 63) wsum[w] = inc;
    __syncthreads();
    int wbase = 0;
    for (int i = 0; i < w; ++i) wbase += wsum[i];
    int ex = bsums[b] + wbase + (inc - s);
    #pragma unroll
    for (int k = 0; k < 4; ++k) {
        int i = base + k;
        if (i < NN) { off[i] = ex; cur[i] = ex; }
        ex += v[k];
    }
}

__global__ __launch_bounds__(256) void fill_kernel(const int* __restrict__ src,
                                                   const int* __restrict__ dst,
                                                   int* __restrict__ cur,
                                                   int* __restrict__ srcs) {
    int e = blockIdx.x * 256 + threadIdx.x;
    if (e < NE) {
        int p = atomicAdd(&cur[dst[e]], 1);
        srcs[p] = src[e];
    }
}

__global__ __launch_bounds__(256) void agg1f_kernel(const float* __restrict__ x,
                                                    const int* __restrict__ srcs,
                                                    const int* __restrict__ off,
                                                    const int* __restrict__ cnt,
                                                    float* __restrict__ mean1) {
    int t = threadIdx.x;
    int n = blockIdx.x * 4 + (t >> 6);
    int d = t & 63;
    int s0 = off[n], deg = cnt[n];
    float acc = 0.f;
    for (int e = 0; e < deg; ++e) acc += x[(size_t)srcs[s0 + e] * IND + d];
    mean1[(size_t)n * HID + d] = acc / fmaxf((float)deg, 1.f);
}

__global__ __launch_bounds__(256) void agg2f_kernel(const float* __restrict__ h1,
                                                    const int* __restrict__ srcs,
                                                    const int* __restrict__ off,
                                                    const int* __restrict__ cnt,
                                                    float* __restrict__ mean2) {
    int t = threadIdx.x;
    int n = blockIdx.x * 2 + (t >> 7);
    int d = t & 127;
    int s0 = off[n], deg = cnt[n];
    float acc = 0.f;
    for (int e = 0; e < deg; ++e) acc += h1[(size_t)srcs[s0 + e] * HID + d];
    mean2[(size_t)n * HID + d] = acc / fmaxf((float)deg, 1.f);
}

__global__ __launch_bounds__(256) void gemm1f_kernel(const float* __restrict__ x,
                                                     const float* __restrict__ Wl,
                                                     const float* __restrict__ Wr,
                                                     const float* __restrict__ b,
                                                     float* __restrict__ h1) {
    __shared__ float in[16][128];
    int t = threadIdx.x;
    int node0 = blockIdx.x * 16;
    for (int idx = t; idx < 16 * 128; idx += 256) {
        int r = idx >> 7, c = idx & 127;
        in[r][c] = (c < IND) ? x[(size_t)(node0 + r) * IND + c]
                             : h1[(size_t)(node0 + r) * HID + (c - IND)];
    }
    __syncthreads();
    int j = t & 127, g = t >> 7;
    float acc[8];
    float bj = b[j];
    #pragma unroll
    for (int q = 0; q < 8; ++q) acc[q] = bj;
    for (int k = 0; k < 128; ++k) {
        float wv = (k < IND) ? Wr[k * HID + j] : Wl[(k - IND) * HID + j];
        #pragma unroll
        for (int q = 0; q < 8; ++q) acc[q] += in[g * 8 + q][k] * wv;
    }
    #pragma unroll
    for (int q = 0; q < 8; ++q)
        h1[(size_t)(node0 + g * 8 + q) * HID + j] = fmaxf(acc[q], 0.f);
}

__global__ __launch_bounds__(256) void gemm2f_kernel(const float* __restrict__ h1,
                                                     const float* __restrict__ Wl,
                                                     const float* __restrict__ Wr,
                                                     const float* __restrict__ b,
                                                     const float* __restrict__ Wout,
                                                     const float* __restrict__ bout,
                                                     float* __restrict__ h2,
                                                     float* __restrict__ out) {
    __shared__ float in[16][256];
    __shared__ float part[4][8];
    int t = threadIdx.x;
    int node0 = blockIdx.x * 16;
    for (int idx = t; idx < 16 * 256; idx += 256) {
        int r = idx >> 8, c = idx & 255;
        in[r][c] = (c < HID) ? h1[(size_t)(node0 + r) * HID + c]
                             : h2[(size_t)(node0 + r) * HID + (c - HID)];
    }
    __syncthreads();
    int j = t & 127, g = t >> 7, lane = t & 63, w = t >> 6;
    float acc[8];
    float bj = b[j];
    #pragma unroll
    for (int q = 0; q < 8; ++q) acc[q] = bj;
    for (int k = 0; k < 256; ++k) {
        float wv = (k < HID) ? Wr[k * HID + j] : Wl[(k - HID) * HID + j];
        #pragma unroll
        for (int q = 0; q < 8; ++q) acc[q] += in[g * 8 + q][k] * wv;
    }
    float wo = Wout[j];
    #pragma unroll
    for (int q = 0; q < 8; ++q)
        h2[(size_t)(node0 + g * 8 + q) * HID + j] = acc[q];
    #pragma unroll
    for (int q = 0; q < 8; ++q) {
        float v = acc[q] * wo;
        #pragma unroll
        for (int o = 32; o > 0; o >>= 1) v += __shfl_down(v, o);
        if (lane == 0) part[w][q] = v;
    }
    __syncthreads();
    if (t < 16) {
        int gg = t >> 3, q = t & 7;
        out[node0 + t] = part[2 * gg][q] + part[2 * gg + 1][q] + bout[0];
    }
}

// ============================ launch ============================

extern "C" void kernel_launch(void* const* d_in, const int* in_sizes, int n_in,
                              void* d_out, int out_size, void* d_ws, size_t ws_size,
                              hipStream_t stream) {
    const float* x    = (const float*)d_in[0];
    const int*   eidx = (const int*)d_in[1];
    const int*   src  = eidx;
    const int*   dst  = eidx + NE;
    const float* Wl1  = (const float*)d_in[2];
    const float* Wr1  = (const float*)d_in[3];
    const float* b1   = (const float*)d_in[4];
    const float* Wl2  = (const float*)d_in[5];
    const float* Wr2  = (const float*)d_in[6];
    const float* b2   = (const float*)d_in[7];
    const float* Wout = (const float*)d_in[8];
    const float* bout = (const float*)d_in[9];

    float* out = (float*)d_out;
    float* h1f = out + NN;
    float* h2f = h1f + (size_t)NN * HID;

    // ---- v4 workspace layout (~28 MB) ----
    char* p = (char*)d_ws;
    int* cnt        = (int*)p;            p += (size_t)NN * 4;
    int* off        = (int*)p;            p += (size_t)NN * 4;
    int* bktcur     = (int*)p;            p += 512 * 4;
    unsigned* bins  = (unsigned*)p;       p += (size_t)NBKT2 * CAP * 4; // 7.8MB (becomes srcs)
    unsigned char* xq  = (unsigned char*)p;   p += (size_t)NN * IND;    // 6.4MB
    unsigned char* h1q = (unsigned char*)p;   p += (size_t)NN * HID;    // 12.8MB
    unsigned short* Wp1 = (unsigned short*)p; p += 8 * 4 * 64 * 8 * 2;  // 32KB
    unsigned short* Wp2 = (unsigned short*)p; p += 8 * 8 * 64 * 8 * 2;  // 64KB
    const size_t need_v4 = (size_t)(p - (char*)d_ws);
    const size_t need_csr = ((size_t)3 * NN + 128 + NE) * sizeof(int);

    if (ws_size >= need_v4) {
        // CSR build v3 (fixed-capacity buckets, in-place permute)
        zero_small_kernel<<<1, 512, 0, stream>>>(bktcur, NBKT2);
        binA_kernel<<<NBLK_E, 512, 0, stream>>>(src, dst, bktcur, bins);
        binB_kernel<<<NBKT2, 256, 0, stream>>>(bktcur, bins, cnt, off);
        // conversions / weight packing
        cvt_xq_kernel<<<(NN * IND / 4) / 256, 256, 0, stream>>>((const float4*)x, (unsigned*)xq);
        packW_kernel<<<8, 256, 0, stream>>>(Wr1, Wl1, IND, 4, Wp1);
        packW_kernel<<<16, 256, 0, stream>>>(Wr2, Wl2, HID, 8, Wp2);
        // fused layers
        fused1_kernel<<<(NN + 63) / 64, 256, 0, stream>>>(x, xq, (const int*)bins, off, cnt,
                                                          Wp1, b1, h1f, h1q);
        fused2_kernel<<<(NN + 63) / 64, 256, 0, stream>>>(h1f, h1q, (const int*)bins, off, cnt,
                                                          Wp2, b2, Wout, bout, h2f, out);
    } else if (ws_size >= need_csr) {
        // fp32 CSR fallback
        int* cntF   = (int*)d_ws;
        int* offF   = cntF + NN;
        int* curF   = offF + NN;
        int* bsums  = curF + NN;
        int* srcsF  = bsums + 128;
        zero_int_kernel<<<(NN / 4 + 255) / 256, 256, 0, stream>>>((int4*)cntF, NN / 4);
        hist_kernel<<<(NE + 255) / 256, 256, 0, stream>>>(dst, cntF);
        scanA_kernel<<<NSB, 256, 0, stream>>>(cntF, bsums);
        scanB_kernel<<<1, 1, 0, stream>>>(bsums);
        scanC_kernel<<<NSB, 256, 0, stream>>>(cntF, bsums, offF, curF);
        fill_kernel<<<(NE + 255) / 256, 256, 0, stream>>>(src, dst, curF, srcsF);
        agg1f_kernel<<<NN / 4, 256, 0, stream>>>(x, srcsF, offF, cntF, h1f);
        gemm1f_kernel<<<NN / 16, 256, 0, stream>>>(x, Wl1, Wr1, b1, h1f);
        agg2f_kernel<<<NN / 2, 256, 0, stream>>>(h1f, srcsF, offF, cntF, h2f);
        gemm2f_kernel<<<NN / 16, 256, 0, stream>>>(h1f, Wl2, Wr2, b2, Wout, bout, h2f, out);
    }
}

// Round 7
// 226.722 us; speedup vs baseline: 1.3186x; 1.3186x over previous
//
#include <hip/hip_runtime.h>

#define NN 100000
#define IND 64
#define HID 128
#define NE 1600000

// ---- CSR build v3: fixed-capacity 256-node buckets ----
#define BKT2 256
#define NBKT2 ((NN + BKT2 - 1) / BKT2)     // 391 buckets
#define CAP 4992                           // mean 4092 + ~14 sigma
#define EPB 4096
#define NBLK_E ((NE + EPB - 1) / EPB)      // 391 edge chunks

// ---- prep kernel block ranges ----
#define CVT_BLKS (NN * IND / 4 / 256)      // 6250
#define PW1_BLKS 8                         // 8*4*64/256
#define PW2_BLKS 16                        // 8*8*64/256

// ---- fallback fp32 CSR path ----
#define SCAN_CHUNK 1024
#define NSB ((NN + SCAN_CHUNK - 1) / SCAN_CHUNK)

typedef __attribute__((ext_vector_type(8))) short bf16x8;
typedef __attribute__((ext_vector_type(4))) float f32x4;
typedef __attribute__((ext_vector_type(2))) float f32x2;

static __device__ __forceinline__ unsigned short f2bf(float f) {
    unsigned u = __float_as_uint(f);
    u = (u + 0x7FFFu + ((u >> 16) & 1u)) >> 16;   // RNE
    return (unsigned short)u;
}
static __device__ __forceinline__ unsigned pack2(float a, float b) {
    return (unsigned)f2bf(a) | ((unsigned)f2bf(b) << 16);
}

// ===================== prep: cvt_xq + packW1 + packW2 + zero =====================

static __device__ __forceinline__ void packW_body(const float* __restrict__ Wr,
                                                  const float* __restrict__ Wl,
                                                  int Khalf, int KS, int t,
                                                  unsigned short* __restrict__ Wp) {
    if (t >= 8 * KS * 64) return;
    int l  = t & 63;
    int ks = (t >> 6) % KS;
    int jt = t / (64 * KS);
    int j  = jt * 16 + (l & 15);
    int kb = ks * 32 + (l >> 4) * 8;
    unsigned short v[8];
    #pragma unroll
    for (int i = 0; i < 8; ++i) {
        int k = kb + i;
        float w = (k < Khalf) ? Wr[k * HID + j] : Wl[(k - Khalf) * HID + j];
        v[i] = f2bf(w);
    }
    ushort4 lo, hi;
    lo.x = v[0]; lo.y = v[1]; lo.z = v[2]; lo.w = v[3];
    hi.x = v[4]; hi.y = v[5]; hi.z = v[6]; hi.w = v[7];
    ushort4* d = reinterpret_cast<ushort4*>(Wp + (size_t)t * 8);
    d[0] = lo; d[1] = hi;
}

__global__ __launch_bounds__(256) void prep_kernel(const float4* __restrict__ x,
                                                   unsigned* __restrict__ xq,
                                                   const float* __restrict__ Wr1,
                                                   const float* __restrict__ Wl1,
                                                   unsigned short* __restrict__ Wp1,
                                                   const float* __restrict__ Wr2,
                                                   const float* __restrict__ Wl2,
                                                   unsigned short* __restrict__ Wp2,
                                                   int* __restrict__ bktcur) {
    int blk = blockIdx.x, t = threadIdx.x;
    if (blk < CVT_BLKS) {
        int i = blk * 256 + t;
        float4 v = x[i];
        int u = __builtin_amdgcn_cvt_pk_fp8_f32(v.x, v.y, 0, false);
        u = __builtin_amdgcn_cvt_pk_fp8_f32(v.z, v.w, u, true);
        xq[i] = (unsigned)u;
    } else if (blk < CVT_BLKS + PW1_BLKS) {
        packW_body(Wr1, Wl1, IND, 4, (blk - CVT_BLKS) * 256 + t, Wp1);
    } else if (blk < CVT_BLKS + PW1_BLKS + PW2_BLKS) {
        packW_body(Wr2, Wl2, HID, 8, (blk - CVT_BLKS - PW1_BLKS) * 256 + t, Wp2);
    } else {
        bktcur[t] = 0;
        bktcur[t + 256] = 0;
    }
}

// ===================== CSR build v3 =====================

__global__ __launch_bounds__(512) void binA_kernel(const int* __restrict__ src,
                                                   const int* __restrict__ dst,
                                                   int* __restrict__ bktcur,
                                                   unsigned* __restrict__ bins) {
    __shared__ int hcnt[NBKT2];
    __shared__ int rbase[NBKT2];
    int t = threadIdx.x;
    int e0 = blockIdx.x * EPB;
    int ce = min(EPB, NE - e0);
    for (int i = t; i < NBKT2; i += 512) hcnt[i] = 0;
    __syncthreads();
    for (int i = t; i < ce; i += 512)
        atomicAdd(&hcnt[dst[e0 + i] >> 8], 1);
    __syncthreads();
    for (int i = t; i < NBKT2; i += 512) {
        int c = hcnt[i];
        rbase[i] = c ? atomicAdd(&bktcur[i], c) : 0;
        hcnt[i] = 0;
    }
    __syncthreads();
    for (int i = t; i < ce; i += 512) {
        int d = dst[e0 + i];
        int b = d >> 8;
        int r = atomicAdd(&hcnt[b], 1);
        bins[(size_t)b * CAP + rbase[b] + r] =
            (unsigned)src[e0 + i] | ((unsigned)(d & 255) << 17);
    }
}

__global__ __launch_bounds__(512) void binB_kernel(const int* __restrict__ bktcur,
                                                   unsigned* __restrict__ bins,
                                                   int* __restrict__ cnt,
                                                   int* __restrict__ off) {
    __shared__ unsigned ebuf[CAP];
    __shared__ int ncnt[BKT2];
    __shared__ int nofs[BKT2];
    __shared__ int wtot[4];
    int t = threadIdx.x, lane = t & 63, w = t >> 6;
    int b = blockIdx.x;
    int m = bktcur[b];
    size_t base = (size_t)b * CAP;
    for (int i = t; i < m; i += 512) ebuf[i] = bins[base + i];
    if (t < BKT2) ncnt[t] = 0;
    __syncthreads();
    for (int i = t; i < m; i += 512)
        atomicAdd(&ncnt[ebuf[i] >> 17], 1);
    __syncthreads();
    if (t < BKT2) {
        int v = ncnt[t];
        int incl = v;
        #pragma unroll
        for (int o = 1; o < 64; o <<= 1) {
            int u = __shfl_up(incl, o);
            if (lane >= o) incl += u;
        }
        if (lane == 63) wtot[w] = incl;
        // wave-local portion done; cross-wave base added after barrier
        nofs[t] = incl - v;
    }
    __syncthreads();
    if (t < BKT2) {
        int wbase = 0;
        #pragma unroll
        for (int i = 0; i < 4; ++i) if (i < w) wbase += wtot[i];
        int ex = nofs[t] + wbase;
        nofs[t] = ex;
        int node = b * BKT2 + t;
        if (node < NN) { cnt[node] = ncnt[t]; off[node] = (int)base + ex; }
    }
    __syncthreads();
    for (int i = t; i < m; i += 512) {
        unsigned val = ebuf[i];
        int r = atomicAdd(&nofs[val >> 17], 1);
        bins[base + r] = val & 0x1FFFFu;
    }
}

// ===================== fp8 gather means =====================

// 64 dims; 16 lanes/row (4 dims/lane), 4-edge parallel, 16-deep pipeline
__global__ __launch_bounds__(256) void agg1_kernel(const unsigned char* __restrict__ xq,
                                                   const int* __restrict__ srcs,
                                                   const int* __restrict__ off,
                                                   const int* __restrict__ cnt,
                                                   unsigned short* __restrict__ m1b) {
    int t = threadIdx.x;
    int n = blockIdx.x * 4 + (t >> 6);
    int l = t & 63, ep = l >> 4, d4 = (l & 15) * 4;
    int s0 = off[n], deg = cnt[n];
    float a0 = 0.f, a1 = 0.f, a2 = 0.f, a3 = 0.f;
    int e = ep;
    for (; e + 12 < deg; e += 16) {
        int sA = srcs[s0 + e],     sB = srcs[s0 + e + 4];
        int sC = srcs[s0 + e + 8], sD = srcs[s0 + e + 12];
        unsigned uA = *reinterpret_cast<const unsigned*>(xq + (size_t)sA * IND + d4);
        unsigned uB = *reinterpret_cast<const unsigned*>(xq + (size_t)sB * IND + d4);
        unsigned uC = *reinterpret_cast<const unsigned*>(xq + (size_t)sC * IND + d4);
        unsigned uD = *reinterpret_cast<const unsigned*>(xq + (size_t)sD * IND + d4);
        f32x2 lA = __builtin_amdgcn_cvt_pk_f32_fp8((int)uA, false);
        f32x2 hA = __builtin_amdgcn_cvt_pk_f32_fp8((int)uA, true);
        f32x2 lB = __builtin_amdgcn_cvt_pk_f32_fp8((int)uB, false);
        f32x2 hB = __builtin_amdgcn_cvt_pk_f32_fp8((int)uB, true);
        f32x2 lC = __builtin_amdgcn_cvt_pk_f32_fp8((int)uC, false);
        f32x2 hC = __builtin_amdgcn_cvt_pk_f32_fp8((int)uC, true);
        f32x2 lD = __builtin_amdgcn_cvt_pk_f32_fp8((int)uD, false);
        f32x2 hD = __builtin_amdgcn_cvt_pk_f32_fp8((int)uD, true);
        a0 += (lA.x + lB.x) + (lC.x + lD.x);
        a1 += (lA.y + lB.y) + (lC.y + lD.y);
        a2 += (hA.x + hB.x) + (hC.x + hD.x);
        a3 += (hA.y + hB.y) + (hC.y + hD.y);
    }
    for (; e < deg; e += 4) {
        int s = srcs[s0 + e];
        unsigned u = *reinterpret_cast<const unsigned*>(xq + (size_t)s * IND + d4);
        f32x2 lo = __builtin_amdgcn_cvt_pk_f32_fp8((int)u, false);
        f32x2 hi = __builtin_amdgcn_cvt_pk_f32_fp8((int)u, true);
        a0 += lo.x; a1 += lo.y; a2 += hi.x; a3 += hi.y;
    }
    a0 += __shfl_down(a0, 32); a1 += __shfl_down(a1, 32);
    a2 += __shfl_down(a2, 32); a3 += __shfl_down(a3, 32);
    a0 += __shfl_down(a0, 16); a1 += __shfl_down(a1, 16);
    a2 += __shfl_down(a2, 16); a3 += __shfl_down(a3, 16);
    if (l < 16) {
        float inv = 1.f / fmaxf((float)deg, 1.f);
        uint2 o;
        o.x = pack2(a0 * inv, a1 * inv);
        o.y = pack2(a2 * inv, a3 * inv);
        *reinterpret_cast<uint2*>(m1b + (size_t)n * IND + d4) = o;
    }
}

// 128 dims; 32 lanes/row (4 dims/lane), 2-edge parallel, 16-deep pipeline
__global__ __launch_bounds__(256) void agg2_kernel(const unsigned char* __restrict__ h1q,
                                                   const int* __restrict__ srcs,
                                                   const int* __restrict__ off,
                                                   const int* __restrict__ cnt,
                                                   unsigned short* __restrict__ m2b) {
    int t = threadIdx.x;
    int n = blockIdx.x * 4 + (t >> 6);
    int l = t & 63, ep = l >> 5, d4 = (l & 31) * 4;
    int s0 = off[n], deg = cnt[n];
    float a0 = 0.f, a1 = 0.f, a2 = 0.f, a3 = 0.f;
    int e = ep;
    for (; e + 14 < deg; e += 16) {
        int sA = srcs[s0 + e],      sB = srcs[s0 + e + 2];
        int sC = srcs[s0 + e + 4],  sD = srcs[s0 + e + 6];
        int sE = srcs[s0 + e + 8],  sF = srcs[s0 + e + 10];
        int sG = srcs[s0 + e + 12], sH = srcs[s0 + e + 14];
        unsigned uA = *reinterpret_cast<const unsigned*>(h1q + (size_t)sA * HID + d4);
        unsigned uB = *reinterpret_cast<const unsigned*>(h1q + (size_t)sB * HID + d4);
        unsigned uC = *reinterpret_cast<const unsigned*>(h1q + (size_t)sC * HID + d4);
        unsigned uD = *reinterpret_cast<const unsigned*>(h1q + (size_t)sD * HID + d4);
        unsigned uE = *reinterpret_cast<const unsigned*>(h1q + (size_t)sE * HID + d4);
        unsigned uF = *reinterpret_cast<const unsigned*>(h1q + (size_t)sF * HID + d4);
        unsigned uG = *reinterpret_cast<const unsigned*>(h1q + (size_t)sG * HID + d4);
        unsigned uH = *reinterpret_cast<const unsigned*>(h1q + (size_t)sH * HID + d4);
        f32x2 lA = __builtin_amdgcn_cvt_pk_f32_fp8((int)uA, false);
        f32x2 hA = __builtin_amdgcn_cvt_pk_f32_fp8((int)uA, true);
        f32x2 lB = __builtin_amdgcn_cvt_pk_f32_fp8((int)uB, false);
        f32x2 hB = __builtin_amdgcn_cvt_pk_f32_fp8((int)uB, true);
        f32x2 lC = __builtin_amdgcn_cvt_pk_f32_fp8((int)uC, false);
        f32x2 hC = __builtin_amdgcn_cvt_pk_f32_fp8((int)uC, true);
        f32x2 lD = __builtin_amdgcn_cvt_pk_f32_fp8((int)uD, false);
        f32x2 hD = __builtin_amdgcn_cvt_pk_f32_fp8((int)uD, true);
        f32x2 lE = __builtin_amdgcn_cvt_pk_f32_fp8((int)uE, false);
        f32x2 hE = __builtin_amdgcn_cvt_pk_f32_fp8((int)uE, true);
        f32x2 lF = __builtin_amdgcn_cvt_pk_f32_fp8((int)uF, false);
        f32x2 hF = __builtin_amdgcn_cvt_pk_f32_fp8((int)uF, true);
        f32x2 lG = __builtin_amdgcn_cvt_pk_f32_fp8((int)uG, false);
        f32x2 hG = __builtin_amdgcn_cvt_pk_f32_fp8((int)uG, true);
        f32x2 lH = __builtin_amdgcn_cvt_pk_f32_fp8((int)uH, false);
        f32x2 hH = __builtin_amdgcn_cvt_pk_f32_fp8((int)uH, true);
        a0 += ((lA.x + lB.x) + (lC.x + lD.x)) + ((lE.x + lF.x) + (lG.x + lH.x));
        a1 += ((lA.y + lB.y) + (lC.y + lD.y)) + ((lE.y + lF.y) + (lG.y + lH.y));
        a2 += ((hA.x + hB.x) + (hC.x + hD.x)) + ((hE.x + hF.x) + (hG.x + hH.x));
        a3 += ((hA.y + hB.y) + (hC.y + hD.y)) + ((hE.y + hF.y) + (hG.y + hH.y));
    }
    for (; e < deg; e += 2) {
        int s = srcs[s0 + e];
        unsigned u = *reinterpret_cast<const unsigned*>(h1q + (size_t)s * HID + d4);
        f32x2 lo = __builtin_amdgcn_cvt_pk_f32_fp8((int)u, false);
        f32x2 hi = __builtin_amdgcn_cvt_pk_f32_fp8((int)u, true);
        a0 += lo.x; a1 += lo.y; a2 += hi.x; a3 += hi.y;
    }
    a0 += __shfl_down(a0, 32); a1 += __shfl_down(a1, 32);
    a2 += __shfl_down(a2, 32); a3 += __shfl_down(a3, 32);
    if (l < 32) {
        float inv = 1.f / fmaxf((float)deg, 1.f);
        uint2 o;
        o.x = pack2(a0 * inv, a1 * inv);
        o.y = pack2(a2 * inv, a3 * inv);
        *reinterpret_cast<uint2*>(m2b + (size_t)n * HID + d4) = o;
    }
}

// ===================== MFMA dense layers =====================

// layer1: h1 = relu([x | m1b] @ Wp1 + b1); reads x fp32 directly
__global__ __launch_bounds__(256) void mfma1_kernel(const float* __restrict__ x,
                                                    const unsigned short* __restrict__ m1b,
                                                    const unsigned short* __restrict__ Wp,
                                                    const float* __restrict__ b,
                                                    float* __restrict__ h1f,
                                                    unsigned short* __restrict__ h1b,
                                                    unsigned char* __restrict__ h1q) {
    int t = threadIdx.x, w = t >> 6, l = t & 63;
    int row0 = blockIdx.x * 64 + w * 16;
    int arow = row0 + (l & 15); if (arow > NN - 1) arow = NN - 1;
    int kcol = (l >> 4) * 8;
    f32x4 acc[8];
    #pragma unroll
    for (int jt = 0; jt < 8; ++jt) { acc[jt][0] = 0.f; acc[jt][1] = 0.f; acc[jt][2] = 0.f; acc[jt][3] = 0.f; }
    #pragma unroll
    for (int ks = 0; ks < 4; ++ks) {
        bf16x8 a;
        int c = (ks & 1) * 32 + kcol;
        if (ks < 2) {
            const float* xr = x + (size_t)arow * IND + c;
            float4 f0 = *reinterpret_cast<const float4*>(xr);
            float4 f1 = *reinterpret_cast<const float4*>(xr + 4);
            a[0] = (short)f2bf(f0.x); a[1] = (short)f2bf(f0.y);
            a[2] = (short)f2bf(f0.z); a[3] = (short)f2bf(f0.w);
            a[4] = (short)f2bf(f1.x); a[5] = (short)f2bf(f1.y);
            a[6] = (short)f2bf(f1.z); a[7] = (short)f2bf(f1.w);
        } else {
            a = *reinterpret_cast<const bf16x8*>(m1b + (size_t)arow * IND + c);
        }
        #pragma unroll
        for (int jt = 0; jt < 8; ++jt) {
            bf16x8 bb = *reinterpret_cast<const bf16x8*>(Wp + ((size_t)(jt * 4 + ks) * 64 + l) * 8);
            acc[jt] = __builtin_amdgcn_mfma_f32_16x16x32_bf16(a, bb, acc[jt], 0, 0, 0);
        }
    }
    int rbase = row0 + (l >> 4) * 4;
    #pragma unroll
    for (int jt = 0; jt < 8; ++jt) {
        int col = jt * 16 + (l & 15);
        float bias = b[col];
        #pragma unroll
        for (int r = 0; r < 4; ++r) {
            int row = rbase + r;
            if (row < NN) {
                float v = fmaxf(acc[jt][r] + bias, 0.f);
                h1f[(size_t)row * HID + col] = v;
                h1b[(size_t)row * HID + col] = f2bf(v);
                unsigned q8 = (unsigned)__builtin_amdgcn_cvt_pk_fp8_f32(v, 0.f, 0, false) & 0xFFu;
                h1q[(size_t)row * HID + col] = (unsigned char)q8;
            }
        }
    }
}

// layer2 + head: h2 = [h1b | m2b] @ Wp2 + b2; out = h2 @ Wout + bout
__global__ __launch_bounds__(256) void mfma2_kernel(const unsigned short* __restrict__ h1b,
                                                    const unsigned short* __restrict__ m2b,
                                                    const unsigned short* __restrict__ Wp,
                                                    const float* __restrict__ b,
                                                    const float* __restrict__ Wout,
                                                    const float* __restrict__ bout,
                                                    float* __restrict__ h2f,
                                                    float* __restrict__ out) {
    int t = threadIdx.x, w = t >> 6, l = t & 63;
    int row0 = blockIdx.x * 64 + w * 16;
    int arow = row0 + (l & 15); if (arow > NN - 1) arow = NN - 1;
    int kcol = (l >> 4) * 8;
    f32x4 acc[8];
    #pragma unroll
    for (int jt = 0; jt < 8; ++jt) { acc[jt][0] = 0.f; acc[jt][1] = 0.f; acc[jt][2] = 0.f; acc[jt][3] = 0.f; }
    #pragma unroll
    for (int ks = 0; ks < 8; ++ks) {
        const unsigned short* A = (ks < 4) ? h1b : m2b;
        int c = (ks & 3) * 32 + kcol;
        bf16x8 a = *reinterpret_cast<const bf16x8*>(A + (size_t)arow * HID + c);
        #pragma unroll
        for (int jt = 0; jt < 8; ++jt) {
            bf16x8 bb = *reinterpret_cast<const bf16x8*>(Wp + ((size_t)(jt * 8 + ks) * 64 + l) * 8);
            acc[jt] = __builtin_amdgcn_mfma_f32_16x16x32_bf16(a, bb, acc[jt], 0, 0, 0);
        }
    }
    int rbase = row0 + (l >> 4) * 4;
    float hs0 = 0.f, hs1 = 0.f, hs2 = 0.f, hs3 = 0.f;
    #pragma unroll
    for (int jt = 0; jt < 8; ++jt) {
        int col = jt * 16 + (l & 15);
        float bias = b[col];
        float wo = Wout[col];
        #pragma unroll
        for (int r = 0; r < 4; ++r) {
            int row = rbase + r;
            float v = acc[jt][r] + bias;
            if (row < NN) h2f[(size_t)row * HID + col] = v;
            if (r == 0) hs0 += v * wo;
            else if (r == 1) hs1 += v * wo;
            else if (r == 2) hs2 += v * wo;
            else hs3 += v * wo;
        }
    }
    #pragma unroll
    for (int o = 1; o < 16; o <<= 1) {
        hs0 += __shfl_xor(hs0, o);
        hs1 += __shfl_xor(hs1, o);
        hs2 += __shfl_xor(hs2, o);
        hs3 += __shfl_xor(hs3, o);
    }
    if ((l & 15) == 0) {
        float bo = bout[0];
        if (rbase + 0 < NN) out[rbase + 0] = hs0 + bo;
        if (rbase + 1 < NN) out[rbase + 1] = hs1 + bo;
        if (rbase + 2 < NN) out[rbase + 2] = hs2 + bo;
        if (rbase + 3 < NN) out[rbase + 3] = hs3 + bo;
    }
}

// ===================== fp32 CSR fallback (round-2) =====================

__global__ __launch_bounds__(256) void zero_int_kernel(int4* __restrict__ p, int n4) {
    int i = blockIdx.x * 256 + threadIdx.x;
    if (i < n4) p[i] = make_int4(0, 0, 0, 0);
}

__global__ __launch_bounds__(256) void hist_kernel(const int* __restrict__ dst,
                                                   int* __restrict__ cnt) {
    int e = blockIdx.x * 256 + threadIdx.x;
    if (e < NE) atomicAdd(&cnt[dst[e]], 1);
}

__global__ __launch_bounds__(256) void scanA_kernel(const int* __restrict__ cnt,
                                                    int* __restrict__ bsums) {
    int b = blockIdx.x, t = threadIdx.x;
    int base = b * SCAN_CHUNK + t * 4;
    int s = 0;
    #pragma unroll
    for (int k = 0; k < 4; ++k) { int i = base + k; if (i < NN) s += cnt[i]; }
    #pragma unroll
    for (int o = 32; o > 0; o >>= 1) s += __shfl_down(s, o);
    __shared__ int wsum[4];
    if ((t & 63) == 0) wsum[t >> 6] = s;
    __syncthreads();
    if (t == 0) bsums[b] = wsum[0] + wsum[1] + wsum[2] + wsum[3];
}

__global__ void scanB_kernel(int* __restrict__ bsums) {
    int acc = 0;
    for (int i = 0; i < NSB; ++i) { int v = bsums[i]; bsums[i] = acc; acc += v; }
}

__global__ __launch_bounds__(256) void scanC_kernel(const int* __restrict__ cnt,
                                                    const int* __restrict__ bsums,
                                                    int* __restrict__ off,
                                                    int* __restrict__ cur) {
    int b = blockIdx.x, t = threadIdx.x;
    int lane = t & 63, w = t >> 6;
    int base = b * SCAN_CHUNK + t * 4;
    int v[4]; int s = 0;
    #pragma unroll
    for (int k = 0; k < 4; ++k) {
        int i = base + k;
        v[k] = (i < NN) ? cnt[i] : 0;
        s += v[k];
    }
    int inc = s;
    #pragma unroll
    for (int o = 1; o < 64; o <<= 1) {
        int xv = __shfl_up(inc, o);
        if (lane >= o) inc += xv;
    }
    __shared__ int wsum[4];
    if (lane == 63) wsum[w] = inc;
    __syncthreads();
    int wbase = 0;
    for (int i = 0; i < w; ++i) wbase += wsum[i];
    int ex = bsums[b] + wbase + (inc - s);
    #pragma unroll
    for (int k = 0; k < 4; ++k) {
        int i = base + k;
        if (i < NN) { off[i] = ex; cur[i] = ex; }
        ex += v[k];
    }
}

__global__ __launch_bounds__(256) void fill_kernel(const int* __restrict__ src,
                                                   const int* __restrict__ dst,
                                                   int* __restrict__ cur,
                                                   int* __restrict__ srcs) {
    int e = blockIdx.x * 256 + threadIdx.x;
    if (e < NE) {
        int p = atomicAdd(&cur[dst[e]], 1);
        srcs[p] = src[e];
    }
}

__global__ __launch_bounds__(256) void agg1f_kernel(const float* __restrict__ x,
                                                    const int* __restrict__ srcs,
                                                    const int* __restrict__ off,
                                                    const int* __restrict__ cnt,
                                                    float* __restrict__ mean1) {
    int t = threadIdx.x;
    int n = blockIdx.x * 4 + (t >> 6);
    int d = t & 63;
    int s0 = off[n], deg = cnt[n];
    float acc = 0.f;
    for (int e = 0; e < deg; ++e) acc += x[(size_t)srcs[s0 + e] * IND + d];
    mean1[(size_t)n * HID + d] = acc / fmaxf((float)deg, 1.f);
}

__global__ __launch_bounds__(256) void agg2f_kernel(const float* __restrict__ h1,
                                                    const int* __restrict__ srcs,
                                                    const int* __restrict__ off,
                                                    const int* __restrict__ cnt,
                                                    float* __restrict__ mean2) {
    int t = threadIdx.x;
    int n = blockIdx.x * 2 + (t >> 7);
    int d = t & 127;
    int s0 = off[n], deg = cnt[n];
    float acc = 0.f;
    for (int e = 0; e < deg; ++e) acc += h1[(size_t)srcs[s0 + e] * HID + d];
    mean2[(size_t)n * HID + d] = acc / fmaxf((float)deg, 1.f);
}

__global__ __launch_bounds__(256) void gemm1f_kernel(const float* __restrict__ x,
                                                     const float* __restrict__ Wl,
                                                     const float* __restrict__ Wr,
                                                     const float* __restrict__ b,
                                                     float* __restrict__ h1) {
    __shared__ float in[16][128];
    int t = threadIdx.x;
    int node0 = blockIdx.x * 16;
    for (int idx = t; idx < 16 * 128; idx += 256) {
        int r = idx >> 7, c = idx & 127;
        in[r][c] = (c < IND) ? x[(size_t)(node0 + r) * IND + c]
                             : h1[(size_t)(node0 + r) * HID + (c - IND)];
    }
    __syncthreads();
    int j = t & 127, g = t >> 7;
    float acc[8];
    float bj = b[j];
    #pragma unroll
    for (int q = 0; q < 8; ++q) acc[q] = bj;
    for (int k = 0; k < 128; ++k) {
        float wv = (k < IND) ? Wr[k * HID + j] : Wl[(k - IND) * HID + j];
        #pragma unroll
        for (int q = 0; q < 8; ++q) acc[q] += in[g * 8 + q][k] * wv;
    }
    #pragma unroll
    for (int q = 0; q < 8; ++q)
        h1[(size_t)(node0 + g * 8 + q) * HID + j] = fmaxf(acc[q], 0.f);
}

__global__ __launch_bounds__(256) void gemm2f_kernel(const float* __restrict__ h1,
                                                     const float* __restrict__ Wl,
                                                     const float* __restrict__ Wr,
                                                     const float* __restrict__ b,
                                                     const float* __restrict__ Wout,
                                                     const float* __restrict__ bout,
                                                     float* __restrict__ h2,
                                                     float* __restrict__ out) {
    __shared__ float in[16][256];
    __shared__ float part[4][8];
    int t = threadIdx.x;
    int node0 = blockIdx.x * 16;
    for (int idx = t; idx < 16 * 256; idx += 256) {
        int r = idx >> 8, c = idx & 255;
        in[r][c] = (c < HID) ? h1[(size_t)(node0 + r) * HID + c]
                             : h2[(size_t)(node0 + r) * HID + (c - HID)];
    }
    __syncthreads();
    int j = t & 127, g = t >> 7, lane = t & 63, w = t >> 6;
    float acc[8];
    float bj = b[j];
    #pragma unroll
    for (int q = 0; q < 8; ++q) acc[q] = bj;
    for (int k = 0; k < 256; ++k) {
        float wv = (k < HID) ? Wr[k * HID + j] : Wl[(k - HID) * HID + j];
        #pragma unroll
        for (int q = 0; q < 8; ++q) acc[q] += in[g * 8 + q][k] * wv;
    }
    float wo = Wout[j];
    #pragma unroll
    for (int q = 0; q < 8; ++q)
        h2[(size_t)(node0 + g * 8 + q) * HID + j] = acc[q];
    #pragma unroll
    for (int q = 0; q < 8; ++q) {
        float v = acc[q] * wo;
        #pragma unroll
        for (int o = 32; o > 0; o >>= 1) v += __shfl_down(v, o);
        if (lane == 0) part[w][q] = v;
    }
    __syncthreads();
    if (t < 16) {
        int gg = t >> 3, q = t & 7;
        out[node0 + t] = part[2 * gg][q] + part[2 * gg + 1][q] + bout[0];
    }
}

// ============================ launch ============================

extern "C" void kernel_launch(void* const* d_in, const int* in_sizes, int n_in,
                              void* d_out, int out_size, void* d_ws, size_t ws_size,
                              hipStream_t stream) {
    const float* x    = (const float*)d_in[0];
    const int*   eidx = (const int*)d_in[1];
    const int*   src  = eidx;
    const int*   dst  = eidx + NE;
    const float* Wl1  = (const float*)d_in[2];
    const float* Wr1  = (const float*)d_in[3];
    const float* b1   = (const float*)d_in[4];
    const float* Wl2  = (const float*)d_in[5];
    const float* Wr2  = (const float*)d_in[6];
    const float* b2   = (const float*)d_in[7];
    const float* Wout = (const float*)d_in[8];
    const float* bout = (const float*)d_in[9];

    float* out = (float*)d_out;
    float* h1f = out + NN;
    float* h2f = h1f + (size_t)NN * HID;

    // ---- v3 workspace layout (~92 MB) ----
    char* p = (char*)d_ws;
    int* cnt        = (int*)p;            p += (size_t)NN * 4;
    int* off        = (int*)p;            p += (size_t)NN * 4;
    int* bktcur     = (int*)p;            p += 512 * 4;
    unsigned* bins  = (unsigned*)p;       p += (size_t)NBKT2 * CAP * 4; // 7.8MB (becomes srcs)
    unsigned char* xq  = (unsigned char*)p;   p += (size_t)NN * IND;    // 6.4MB
    unsigned short* m1b = (unsigned short*)p; p += (size_t)NN * IND * 2; // 12.8MB
    unsigned short* h1b = (unsigned short*)p; p += (size_t)NN * HID * 2; // 25.6MB
    unsigned char* h1q  = (unsigned char*)p;  p += (size_t)NN * HID;     // 12.8MB
    unsigned short* m2b = (unsigned short*)p; p += (size_t)NN * HID * 2; // 25.6MB
    unsigned short* Wp1 = (unsigned short*)p; p += 8 * 4 * 64 * 8 * 2;   // 32KB
    unsigned short* Wp2 = (unsigned short*)p; p += 8 * 8 * 64 * 8 * 2;   // 64KB
    const size_t need_v3 = (size_t)(p - (char*)d_ws);
    const size_t need_csr = ((size_t)3 * NN + 128 + NE) * sizeof(int);

    if (ws_size >= need_v3) {
        // prep: fp8 convert + weight packs + zero bucket cursors (1 launch)
        prep_kernel<<<CVT_BLKS + PW1_BLKS + PW2_BLKS + 1, 256, 0, stream>>>(
            (const float4*)x, (unsigned*)xq, Wr1, Wl1, Wp1, Wr2, Wl2, Wp2, bktcur);
        // CSR build (fixed-capacity buckets, in-place permute)
        binA_kernel<<<NBLK_E, 512, 0, stream>>>(src, dst, bktcur, bins);
        binB_kernel<<<NBKT2, 512, 0, stream>>>(bktcur, bins, cnt, off);
        // layer 1
        agg1_kernel<<<NN / 4, 256, 0, stream>>>(xq, (const int*)bins, off, cnt, m1b);
        mfma1_kernel<<<(NN + 63) / 64, 256, 0, stream>>>(x, m1b, Wp1, b1, h1f, h1b, h1q);
        // layer 2 + head
        agg2_kernel<<<NN / 4, 256, 0, stream>>>(h1q, (const int*)bins, off, cnt, m2b);
        mfma2_kernel<<<(NN + 63) / 64, 256, 0, stream>>>(h1b, m2b, Wp2, b2, Wout, bout, h2f, out);
    } else if (ws_size >= need_csr) {
        // fp32 CSR fallback
        int* cntF   = (int*)d_ws;
        int* offF   = cntF + NN;
        int* curF   = offF + NN;
        int* bsums  = curF + NN;
        int* srcsF  = bsums + 128;
        zero_int_kernel<<<(NN / 4 + 255) / 256, 256, 0, stream>>>((int4*)cntF, NN / 4);
        hist_kernel<<<(NE + 255) / 256, 256, 0, stream>>>(dst, cntF);
        scanA_kernel<<<NSB, 256, 0, stream>>>(cntF, bsums);
        scanB_kernel<<<1, 1, 0, stream>>>(bsums);
        scanC_kernel<<<NSB, 256, 0, stream>>>(cntF, bsums, offF, curF);
        fill_kernel<<<(NE + 255) / 256, 256, 0, stream>>>(src, dst, curF, srcsF);
        agg1f_kernel<<<NN / 4, 256, 0, stream>>>(x, srcsF, offF, cntF, h1f);
        gemm1f_kernel<<<NN / 16, 256, 0, stream>>>(x, Wl1, Wr1, b1, h1f);
        agg2f_kernel<<<NN / 2, 256, 0, stream>>>(h1f, srcsF, offF, cntF, h2f);
        gemm2f_kernel<<<NN / 16, 256, 0, stream>>>(h1f, Wl2, Wr2, b2, Wout, bout, h2f, out);
    }
}

// Round 8
// 218.509 us; speedup vs baseline: 1.3682x; 1.0376x over previous
//
#include <hip/hip_runtime.h>

#define NN 100000
#define IND 64
#define HID 128
#define NE 1600000

// ---- CSR build v3: fixed-capacity 256-node buckets ----
#define BKT2 256
#define NBKT2 ((NN + BKT2 - 1) / BKT2)     // 391 buckets
#define CAP 4992                           // mean 4092 + ~14 sigma
#define EPB 4096
#define NBLK_E ((NE + EPB - 1) / EPB)      // 391 edge chunks

// ---- prep kernel block ranges ----
#define CVT_BLKS (NN * IND / 4 / 256)      // 6250
#define PW1_BLKS 8
#define PW2_BLKS 16

// ---- fallback fp32 CSR path ----
#define SCAN_CHUNK 1024
#define NSB ((NN + SCAN_CHUNK - 1) / SCAN_CHUNK)

typedef __attribute__((ext_vector_type(8))) short bf16x8;
typedef __attribute__((ext_vector_type(4))) float f32x4;
typedef __attribute__((ext_vector_type(2))) float f32x2;

static __device__ __forceinline__ unsigned short f2bf(float f) {
    unsigned u = __float_as_uint(f);
    u = (u + 0x7FFFu + ((u >> 16) & 1u)) >> 16;   // RNE
    return (unsigned short)u;
}
static __device__ __forceinline__ unsigned pack2(float a, float b) {
    return (unsigned)f2bf(a) | ((unsigned)f2bf(b) << 16);
}

// ===================== prep: cvt_xq + packW1 + packW2 + zero =====================

static __device__ __forceinline__ void packW_body(const float* __restrict__ Wr,
                                                  const float* __restrict__ Wl,
                                                  int Khalf, int KS, int t,
                                                  unsigned short* __restrict__ Wp) {
    if (t >= 8 * KS * 64) return;
    int l  = t & 63;
    int ks = (t >> 6) % KS;
    int jt = t / (64 * KS);
    int j  = jt * 16 + (l & 15);
    int kb = ks * 32 + (l >> 4) * 8;
    unsigned short v[8];
    #pragma unroll
    for (int i = 0; i < 8; ++i) {
        int k = kb + i;
        float w = (k < Khalf) ? Wr[k * HID + j] : Wl[(k - Khalf) * HID + j];
        v[i] = f2bf(w);
    }
    ushort4 lo, hi;
    lo.x = v[0]; lo.y = v[1]; lo.z = v[2]; lo.w = v[3];
    hi.x = v[4]; hi.y = v[5]; hi.z = v[6]; hi.w = v[7];
    ushort4* d = reinterpret_cast<ushort4*>(Wp + (size_t)t * 8);
    d[0] = lo; d[1] = hi;
}

__global__ __launch_bounds__(256) void prep_kernel(const float4* __restrict__ x,
                                                   unsigned* __restrict__ xq,
                                                   const float* __restrict__ Wr1,
                                                   const float* __restrict__ Wl1,
                                                   unsigned short* __restrict__ Wp1,
                                                   const float* __restrict__ Wr2,
                                                   const float* __restrict__ Wl2,
                                                   unsigned short* __restrict__ Wp2,
                                                   int* __restrict__ bktcur) {
    int blk = blockIdx.x, t = threadIdx.x;
    if (blk < CVT_BLKS) {
        int i = blk * 256 + t;
        float4 v = x[i];
        int u = __builtin_amdgcn_cvt_pk_fp8_f32(v.x, v.y, 0, false);
        u = __builtin_amdgcn_cvt_pk_fp8_f32(v.z, v.w, u, true);
        xq[i] = (unsigned)u;
    } else if (blk < CVT_BLKS + PW1_BLKS) {
        packW_body(Wr1, Wl1, IND, 4, (blk - CVT_BLKS) * 256 + t, Wp1);
    } else if (blk < CVT_BLKS + PW1_BLKS + PW2_BLKS) {
        packW_body(Wr2, Wl2, HID, 8, (blk - CVT_BLKS - PW1_BLKS) * 256 + t, Wp2);
    } else {
        bktcur[t] = 0;
        bktcur[t + 256] = 0;
    }
}

// ===================== CSR build v3 =====================

__global__ __launch_bounds__(512) void binA_kernel(const int* __restrict__ src,
                                                   const int* __restrict__ dst,
                                                   int* __restrict__ bktcur,
                                                   unsigned* __restrict__ bins) {
    __shared__ int hcnt[NBKT2];
    __shared__ int rbase[NBKT2];
    int t = threadIdx.x;
    int e0 = blockIdx.x * EPB;
    int ce = min(EPB, NE - e0);
    for (int i = t; i < NBKT2; i += 512) hcnt[i] = 0;
    __syncthreads();
    for (int i = t; i < ce; i += 512)
        atomicAdd(&hcnt[dst[e0 + i] >> 8], 1);
    __syncthreads();
    for (int i = t; i < NBKT2; i += 512) {
        int c = hcnt[i];
        rbase[i] = c ? atomicAdd(&bktcur[i], c) : 0;
        hcnt[i] = 0;
    }
    __syncthreads();
    for (int i = t; i < ce; i += 512) {
        int d = dst[e0 + i];
        int b = d >> 8;
        int r = atomicAdd(&hcnt[b], 1);
        bins[(size_t)b * CAP + rbase[b] + r] =
            (unsigned)src[e0 + i] | ((unsigned)(d & 255) << 17);
    }
}

__global__ __launch_bounds__(512) void binB_kernel(const int* __restrict__ bktcur,
                                                   unsigned* __restrict__ bins,
                                                   int* __restrict__ cnt,
                                                   int* __restrict__ off) {
    __shared__ unsigned ebuf[CAP];
    __shared__ int ncnt[BKT2];
    __shared__ int nofs[BKT2];
    __shared__ int wtot[4];
    int t = threadIdx.x, lane = t & 63, w = t >> 6;
    int b = blockIdx.x;
    int m = bktcur[b];
    size_t base = (size_t)b * CAP;
    for (int i = t; i < m; i += 512) ebuf[i] = bins[base + i];
    if (t < BKT2) ncnt[t] = 0;
    __syncthreads();
    for (int i = t; i < m; i += 512)
        atomicAdd(&ncnt[ebuf[i] >> 17], 1);
    __syncthreads();
    if (t < BKT2) {
        int v = ncnt[t];
        int incl = v;
        #pragma unroll
        for (int o = 1; o < 64; o <<= 1) {
            int u = __shfl_up(incl, o);
            if (lane >= o) incl += u;
        }
        if (lane == 63) wtot[w] = incl;
        nofs[t] = incl - v;
    }
    __syncthreads();
    if (t < BKT2) {
        int wbase = 0;
        #pragma unroll
        for (int i = 0; i < 4; ++i) if (i < w) wbase += wtot[i];
        int ex = nofs[t] + wbase;
        nofs[t] = ex;
        int node = b * BKT2 + t;
        if (node < NN) { cnt[node] = ncnt[t]; off[node] = (int)base + ex; }
    }
    __syncthreads();
    for (int i = t; i < m; i += 512) {
        unsigned val = ebuf[i];
        int r = atomicAdd(&nofs[val >> 17], 1);
        bins[base + r] = val & 0x1FFFFu;
    }
}

// ===================== fp8 gather means (wide loads) =====================

// agg1: 64B rows; 8 lanes/row (uint2 = 8 dims/lane), 8-edge parallel
__global__ __launch_bounds__(256) void agg1_kernel(const unsigned char* __restrict__ xq,
                                                   const int* __restrict__ srcs,
                                                   const int* __restrict__ off,
                                                   const int* __restrict__ cnt,
                                                   unsigned short* __restrict__ m1b) {
    int t = threadIdx.x;
    int n = blockIdx.x * 4 + (t >> 6);
    int l = t & 63, ep = l >> 3, doff = (l & 7) * 8;
    int s0 = off[n], deg = cnt[n];
    float acc[8];
    #pragma unroll
    for (int i = 0; i < 8; ++i) acc[i] = 0.f;
    int e = ep;
    for (; e + 8 < deg; e += 16) {
        int sA = srcs[s0 + e], sB = srcs[s0 + e + 8];
        uint2 uA = *reinterpret_cast<const uint2*>(xq + (size_t)sA * IND + doff);
        uint2 uB = *reinterpret_cast<const uint2*>(xq + (size_t)sB * IND + doff);
        #pragma unroll
        for (int hw = 0; hw < 2; ++hw) {
            unsigned ua = hw ? uA.y : uA.x;
            unsigned ub = hw ? uB.y : uB.x;
            f32x2 la = __builtin_amdgcn_cvt_pk_f32_fp8((int)ua, false);
            f32x2 ha = __builtin_amdgcn_cvt_pk_f32_fp8((int)ua, true);
            f32x2 lb = __builtin_amdgcn_cvt_pk_f32_fp8((int)ub, false);
            f32x2 hb = __builtin_amdgcn_cvt_pk_f32_fp8((int)ub, true);
            acc[hw * 4 + 0] += la.x + lb.x;
            acc[hw * 4 + 1] += la.y + lb.y;
            acc[hw * 4 + 2] += ha.x + hb.x;
            acc[hw * 4 + 3] += ha.y + hb.y;
        }
    }
    for (; e < deg; e += 8) {
        int s = srcs[s0 + e];
        uint2 u = *reinterpret_cast<const uint2*>(xq + (size_t)s * IND + doff);
        #pragma unroll
        for (int hw = 0; hw < 2; ++hw) {
            unsigned uu = hw ? u.y : u.x;
            f32x2 lo = __builtin_amdgcn_cvt_pk_f32_fp8((int)uu, false);
            f32x2 hi = __builtin_amdgcn_cvt_pk_f32_fp8((int)uu, true);
            acc[hw * 4 + 0] += lo.x; acc[hw * 4 + 1] += lo.y;
            acc[hw * 4 + 2] += hi.x; acc[hw * 4 + 3] += hi.y;
        }
    }
    #pragma unroll
    for (int o = 8; o <= 32; o <<= 1) {
        #pragma unroll
        for (int i = 0; i < 8; ++i) acc[i] += __shfl_xor(acc[i], o);
    }
    if (l < 8) {
        float inv = 1.f / fmaxf((float)deg, 1.f);
        uint4 o;
        o.x = pack2(acc[0] * inv, acc[1] * inv);
        o.y = pack2(acc[2] * inv, acc[3] * inv);
        o.z = pack2(acc[4] * inv, acc[5] * inv);
        o.w = pack2(acc[6] * inv, acc[7] * inv);
        *reinterpret_cast<uint4*>(m1b + (size_t)n * IND + l * 8) = o;
    }
}

// agg2: 128B rows; 8 lanes/row (uint4 = 16 dims/lane), 8-edge parallel
__global__ __launch_bounds__(256) void agg2_kernel(const unsigned char* __restrict__ h1q,
                                                   const int* __restrict__ srcs,
                                                   const int* __restrict__ off,
                                                   const int* __restrict__ cnt,
                                                   unsigned short* __restrict__ m2b) {
    int t = threadIdx.x;
    int n = blockIdx.x * 4 + (t >> 6);
    int l = t & 63, ep = l >> 3, doff = (l & 7) * 16;
    int s0 = off[n], deg = cnt[n];
    float acc[16];
    #pragma unroll
    for (int i = 0; i < 16; ++i) acc[i] = 0.f;
    int e = ep;
    for (; e + 8 < deg; e += 16) {
        int sA = srcs[s0 + e], sB = srcs[s0 + e + 8];
        uint4 uA = *reinterpret_cast<const uint4*>(h1q + (size_t)sA * HID + doff);
        uint4 uB = *reinterpret_cast<const uint4*>(h1q + (size_t)sB * HID + doff);
        unsigned wa[4] = {uA.x, uA.y, uA.z, uA.w};
        unsigned wb[4] = {uB.x, uB.y, uB.z, uB.w};
        #pragma unroll
        for (int q = 0; q < 4; ++q) {
            f32x2 la = __builtin_amdgcn_cvt_pk_f32_fp8((int)wa[q], false);
            f32x2 ha = __builtin_amdgcn_cvt_pk_f32_fp8((int)wa[q], true);
            f32x2 lb = __builtin_amdgcn_cvt_pk_f32_fp8((int)wb[q], false);
            f32x2 hb = __builtin_amdgcn_cvt_pk_f32_fp8((int)wb[q], true);
            acc[q * 4 + 0] += la.x + lb.x;
            acc[q * 4 + 1] += la.y + lb.y;
            acc[q * 4 + 2] += ha.x + hb.x;
            acc[q * 4 + 3] += ha.y + hb.y;
        }
    }
    for (; e < deg; e += 8) {
        int s = srcs[s0 + e];
        uint4 u = *reinterpret_cast<const uint4*>(h1q + (size_t)s * HID + doff);
        unsigned wu[4] = {u.x, u.y, u.z, u.w};
        #pragma unroll
        for (int q = 0; q < 4; ++q) {
            f32x2 lo = __builtin_amdgcn_cvt_pk_f32_fp8((int)wu[q], false);
            f32x2 hi = __builtin_amdgcn_cvt_pk_f32_fp8((int)wu[q], true);
            acc[q * 4 + 0] += lo.x; acc[q * 4 + 1] += lo.y;
            acc[q * 4 + 2] += hi.x; acc[q * 4 + 3] += hi.y;
        }
    }
    #pragma unroll
    for (int o = 8; o <= 32; o <<= 1) {
        #pragma unroll
        for (int i = 0; i < 16; ++i) acc[i] += __shfl_xor(acc[i], o);
    }
    if (l < 8) {
        float inv = 1.f / fmaxf((float)deg, 1.f);
        uint4 o1, o2;
        o1.x = pack2(acc[0] * inv,  acc[1] * inv);
        o1.y = pack2(acc[2] * inv,  acc[3] * inv);
        o1.z = pack2(acc[4] * inv,  acc[5] * inv);
        o1.w = pack2(acc[6] * inv,  acc[7] * inv);
        o2.x = pack2(acc[8] * inv,  acc[9] * inv);
        o2.y = pack2(acc[10] * inv, acc[11] * inv);
        o2.z = pack2(acc[12] * inv, acc[13] * inv);
        o2.w = pack2(acc[14] * inv, acc[15] * inv);
        unsigned short* dstp = m2b + (size_t)n * HID + l * 16;
        *reinterpret_cast<uint4*>(dstp) = o1;
        *reinterpret_cast<uint4*>(dstp + 8) = o2;
    }
}

// ===================== MFMA dense layers =====================

__global__ __launch_bounds__(256) void mfma1_kernel(const float* __restrict__ x,
                                                    const unsigned short* __restrict__ m1b,
                                                    const unsigned short* __restrict__ Wp,
                                                    const float* __restrict__ b,
                                                    float* __restrict__ h1f,
                                                    unsigned short* __restrict__ h1b,
                                                    unsigned char* __restrict__ h1q) {
    int t = threadIdx.x, w = t >> 6, l = t & 63;
    int row0 = blockIdx.x * 64 + w * 16;
    int arow = row0 + (l & 15); if (arow > NN - 1) arow = NN - 1;
    int kcol = (l >> 4) * 8;
    f32x4 acc[8];
    #pragma unroll
    for (int jt = 0; jt < 8; ++jt) { acc[jt][0] = 0.f; acc[jt][1] = 0.f; acc[jt][2] = 0.f; acc[jt][3] = 0.f; }
    #pragma unroll
    for (int ks = 0; ks < 4; ++ks) {
        bf16x8 a;
        int c = (ks & 1) * 32 + kcol;
        if (ks < 2) {
            const float* xr = x + (size_t)arow * IND + c;
            float4 f0 = *reinterpret_cast<const float4*>(xr);
            float4 f1 = *reinterpret_cast<const float4*>(xr + 4);
            a[0] = (short)f2bf(f0.x); a[1] = (short)f2bf(f0.y);
            a[2] = (short)f2bf(f0.z); a[3] = (short)f2bf(f0.w);
            a[4] = (short)f2bf(f1.x); a[5] = (short)f2bf(f1.y);
            a[6] = (short)f2bf(f1.z); a[7] = (short)f2bf(f1.w);
        } else {
            a = *reinterpret_cast<const bf16x8*>(m1b + (size_t)arow * IND + c);
        }
        #pragma unroll
        for (int jt = 0; jt < 8; ++jt) {
            bf16x8 bb = *reinterpret_cast<const bf16x8*>(Wp + ((size_t)(jt * 4 + ks) * 64 + l) * 8);
            acc[jt] = __builtin_amdgcn_mfma_f32_16x16x32_bf16(a, bb, acc[jt], 0, 0, 0);
        }
    }
    int rbase = row0 + (l >> 4) * 4;
    #pragma unroll
    for (int jt = 0; jt < 8; ++jt) {
        int col = jt * 16 + (l & 15);
        float bias = b[col];
        #pragma unroll
        for (int r = 0; r < 4; ++r) {
            int row = rbase + r;
            if (row < NN) {
                float v = fmaxf(acc[jt][r] + bias, 0.f);
                h1f[(size_t)row * HID + col] = v;
                h1b[(size_t)row * HID + col] = f2bf(v);
                unsigned q8 = (unsigned)__builtin_amdgcn_cvt_pk_fp8_f32(v, 0.f, 0, false) & 0xFFu;
                h1q[(size_t)row * HID + col] = (unsigned char)q8;
            }
        }
    }
}

__global__ __launch_bounds__(256) void mfma2_kernel(const unsigned short* __restrict__ h1b,
                                                    const unsigned short* __restrict__ m2b,
                                                    const unsigned short* __restrict__ Wp,
                                                    const float* __restrict__ b,
                                                    const float* __restrict__ Wout,
                                                    const float* __restrict__ bout,
                                                    float* __restrict__ h2f,
                                                    float* __restrict__ out) {
    int t = threadIdx.x, w = t >> 6, l = t & 63;
    int row0 = blockIdx.x * 64 + w * 16;
    int arow = row0 + (l & 15); if (arow > NN - 1) arow = NN - 1;
    int kcol = (l >> 4) * 8;
    f32x4 acc[8];
    #pragma unroll
    for (int jt = 0; jt < 8; ++jt) { acc[jt][0] = 0.f; acc[jt][1] = 0.f; acc[jt][2] = 0.f; acc[jt][3] = 0.f; }
    #pragma unroll
    for (int ks = 0; ks < 8; ++ks) {
        const unsigned short* A = (ks < 4) ? h1b : m2b;
        int c = (ks & 3) * 32 + kcol;
        bf16x8 a = *reinterpret_cast<const bf16x8*>(A + (size_t)arow * HID + c);
        #pragma unroll
        for (int jt = 0; jt < 8; ++jt) {
            bf16x8 bb = *reinterpret_cast<const bf16x8*>(Wp + ((size_t)(jt * 8 + ks) * 64 + l) * 8);
            acc[jt] = __builtin_amdgcn_mfma_f32_16x16x32_bf16(a, bb, acc[jt], 0, 0, 0);
        }
    }
    int rbase = row0 + (l >> 4) * 4;
    float hs0 = 0.f, hs1 = 0.f, hs2 = 0.f, hs3 = 0.f;
    #pragma unroll
    for (int jt = 0; jt < 8; ++jt) {
        int col = jt * 16 + (l & 15);
        float bias = b[col];
        float wo = Wout[col];
        #pragma unroll
        for (int r = 0; r < 4; ++r) {
            int row = rbase + r;
            float v = acc[jt][r] + bias;
            if (row < NN) h2f[(size_t)row * HID + col] = v;
            if (r == 0) hs0 += v * wo;
            else if (r == 1) hs1 += v * wo;
            else if (r == 2) hs2 += v * wo;
            else hs3 += v * wo;
        }
    }
    #pragma unroll
    for (int o = 1; o < 16; o <<= 1) {
        hs0 += __shfl_xor(hs0, o);
        hs1 += __shfl_xor(hs1, o);
        hs2 += __shfl_xor(hs2, o);
        hs3 += __shfl_xor(hs3, o);
    }
    if ((l & 15) == 0) {
        float bo = bout[0];
        if (rbase + 0 < NN) out[rbase + 0] = hs0 + bo;
        if (rbase + 1 < NN) out[rbase + 1] = hs1 + bo;
        if (rbase + 2 < NN) out[rbase + 2] = hs2 + bo;
        if (rbase + 3 < NN) out[rbase + 3] = hs3 + bo;
    }
}

// ===================== fp32 CSR fallback (round-2) =====================

__global__ __launch_bounds__(256) void zero_int_kernel(int4* __restrict__ p, int n4) {
    int i = blockIdx.x * 256 + threadIdx.x;
    if (i < n4) p[i] = make_int4(0, 0, 0, 0);
}

__global__ __launch_bounds__(256) void hist_kernel(const int* __restrict__ dst,
                                                   int* __restrict__ cnt) {
    int e = blockIdx.x * 256 + threadIdx.x;
    if (e < NE) atomicAdd(&cnt[dst[e]], 1);
}

__global__ __launch_bounds__(256) void scanA_kernel(const int* __restrict__ cnt,
                                                    int* __restrict__ bsums) {
    int b = blockIdx.x, t = threadIdx.x;
    int base = b * SCAN_CHUNK + t * 4;
    int s = 0;
    #pragma unroll
    for (int k = 0; k < 4; ++k) { int i = base + k; if (i < NN) s += cnt[i]; }
    #pragma unroll
    for (int o = 32; o > 0; o >>= 1) s += __shfl_down(s, o);
    __shared__ int wsum[4];
    if ((t & 63) == 0) wsum[t >> 6] = s;
    __syncthreads();
    if (t == 0) bsums[b] = wsum[0] + wsum[1] + wsum[2] + wsum[3];
}

__global__ void scanB_kernel(int* __restrict__ bsums) {
    int acc = 0;
    for (int i = 0; i < NSB; ++i) { int v = bsums[i]; bsums[i] = acc; acc += v; }
}

__global__ __launch_bounds__(256) void scanC_kernel(const int* __restrict__ cnt,
                                                    const int* __restrict__ bsums,
                                                    int* __restrict__ off,
                                                    int* __restrict__ cur) {
    int b = blockIdx.x, t = threadIdx.x;
    int lane = t & 63, w = t >> 6;
    int base = b * SCAN_CHUNK + t * 4;
    int v[4]; int s = 0;
    #pragma unroll
    for (int k = 0; k < 4; ++k) {
        int i = base + k;
        v[k] = (i < NN) ? cnt[i] : 0;
        s += v[k];
    }
    int inc = s;
    #pragma unroll
    for (int o = 1; o < 64; o <<= 1) {
        int xv = __shfl_up(inc, o);
        if (lane >= o) inc += xv;
    }
    __shared__ int wsum[4];
    if (lane == 63) wsum[w] = inc;
    __syncthreads();
    int wbase = 0;
    for (int i = 0; i < w; ++i) wbase += wsum[i];
    int ex = bsums[b] + wbase + (inc - s);
    #pragma unroll
    for (int k = 0; k < 4; ++k) {
        int i = base + k;
        if (i < NN) { off[i] = ex; cur[i] = ex; }
        ex += v[k];
    }
}

__global__ __launch_bounds__(256) void fill_kernel(const int* __restrict__ src,
                                                   const int* __restrict__ dst,
                                                   int* __restrict__ cur,
                                                   int* __restrict__ srcs) {
    int e = blockIdx.x * 256 + threadIdx.x;
    if (e < NE) {
        int p = atomicAdd(&cur[dst[e]], 1);
        srcs[p] = src[e];
    }
}

__global__ __launch_bounds__(256) void agg1f_kernel(const float* __restrict__ x,
                                                    const int* __restrict__ srcs,
                                                    const int* __restrict__ off,
                                                    const int* __restrict__ cnt,
                                                    float* __restrict__ mean1) {
    int t = threadIdx.x;
    int n = blockIdx.x * 4 + (t >> 6);
    int d = t & 63;
    int s0 = off[n], deg = cnt[n];
    float acc = 0.f;
    for (int e = 0; e < deg; ++e) acc += x[(size_t)srcs[s0 + e] * IND + d];
    mean1[(size_t)n * HID + d] = acc / fmaxf((float)deg, 1.f);
}

__global__ __launch_bounds__(256) void agg2f_kernel(const float* __restrict__ h1,
                                                    const int* __restrict__ srcs,
                                                    const int* __restrict__ off,
                                                    const int* __restrict__ cnt,
                                                    float* __restrict__ mean2) {
    int t = threadIdx.x;
    int n = blockIdx.x * 2 + (t >> 7);
    int d = t & 127;
    int s0 = off[n], deg = cnt[n];
    float acc = 0.f;
    for (int e = 0; e < deg; ++e) acc += h1[(size_t)srcs[s0 + e] * HID + d];
    mean2[(size_t)n * HID + d] = acc / fmaxf((float)deg, 1.f);
}

__global__ __launch_bounds__(256) void gemm1f_kernel(const float* __restrict__ x,
                                                     const float* __restrict__ Wl,
                                                     const float* __restrict__ Wr,
                                                     const float* __restrict__ b,
                                                     float* __restrict__ h1) {
    __shared__ float in[16][128];
    int t = threadIdx.x;
    int node0 = blockIdx.x * 16;
    for (int idx = t; idx < 16 * 128; idx += 256) {
        int r = idx >> 7, c = idx & 127;
        in[r][c] = (c < IND) ? x[(size_t)(node0 + r) * IND + c]
                             : h1[(size_t)(node0 + r) * HID + (c - IND)];
    }
    __syncthreads();
    int j = t & 127, g = t >> 7;
    float acc[8];
    float bj = b[j];
    #pragma unroll
    for (int q = 0; q < 8; ++q) acc[q] = bj;
    for (int k = 0; k < 128; ++k) {
        float wv = (k < IND) ? Wr[k * HID + j] : Wl[(k - IND) * HID + j];
        #pragma unroll
        for (int q = 0; q < 8; ++q) acc[q] += in[g * 8 + q][k] * wv;
    }
    #pragma unroll
    for (int q = 0; q < 8; ++q)
        h1[(size_t)(node0 + g * 8 + q) * HID + j] = fmaxf(acc[q], 0.f);
}

__global__ __launch_bounds__(256) void gemm2f_kernel(const float* __restrict__ h1,
                                                     const float* __restrict__ Wl,
                                                     const float* __restrict__ Wr,
                                                     const float* __restrict__ b,
                                                     const float* __restrict__ Wout,
                                                     const float* __restrict__ bout,
                                                     float* __restrict__ h2,
                                                     float* __restrict__ out) {
    __shared__ float in[16][256];
    __shared__ float part[4][8];
    int t = threadIdx.x;
    int node0 = blockIdx.x * 16;
    for (int idx = t; idx < 16 * 256; idx += 256) {
        int r = idx >> 8, c = idx & 255;
        in[r][c] = (c < HID) ? h1[(size_t)(node0 + r) * HID + c]
                             : h2[(size_t)(node0 + r) * HID + (c - HID)];
    }
    __syncthreads();
    int j = t & 127, g = t >> 7, lane = t & 63, w = t >> 6;
    float acc[8];
    float bj = b[j];
    #pragma unroll
    for (int q = 0; q < 8; ++q) acc[q] = bj;
    for (int k = 0; k < 256; ++k) {
        float wv = (k < HID) ? Wr[k * HID + j] : Wl[(k - HID) * HID + j];
        #pragma unroll
        for (int q = 0; q < 8; ++q) acc[q] += in[g * 8 + q][k] * wv;
    }
    float wo = Wout[j];
    #pragma unroll
    for (int q = 0; q < 8; ++q)
        h2[(size_t)(node0 + g * 8 + q) * HID + j] = acc[q];
    #pragma unroll
    for (int q = 0; q < 8; ++q) {
        float v = acc[q] * wo;
        #pragma unroll
        for (int o = 32; o > 0; o >>= 1) v += __shfl_down(v, o);
        if (lane == 0) part[w][q] = v;
    }
    __syncthreads();
    if (t < 16) {
        int gg = t >> 3, q = t & 7;
        out[node0 + t] = part[2 * gg][q] + part[2 * gg + 1][q] + bout[0];
    }
}

// ============================ launch ============================

extern "C" void kernel_launch(void* const* d_in, const int* in_sizes, int n_in,
                              void* d_out, int out_size, void* d_ws, size_t ws_size,
                              hipStream_t stream) {
    const float* x    = (const float*)d_in[0];
    const int*   eidx = (const int*)d_in[1];
    const int*   src  = eidx;
    const int*   dst  = eidx + NE;
    const float* Wl1  = (const float*)d_in[2];
    const float* Wr1  = (const float*)d_in[3];
    const float* b1   = (const float*)d_in[4];
    const float* Wl2  = (const float*)d_in[5];
    const float* Wr2  = (const float*)d_in[6];
    const float* b2   = (const float*)d_in[7];
    const float* Wout = (const float*)d_in[8];
    const float* bout = (const float*)d_in[9];

    float* out = (float*)d_out;
    float* h1f = out + NN;
    float* h2f = h1f + (size_t)NN * HID;

    // ---- workspace layout (~92 MB) ----
    char* p = (char*)d_ws;
    int* cnt        = (int*)p;            p += (size_t)NN * 4;
    int* off        = (int*)p;            p += (size_t)NN * 4;
    int* bktcur     = (int*)p;            p += 512 * 4;
    unsigned* bins  = (unsigned*)p;       p += (size_t)NBKT2 * CAP * 4; // 7.8MB (becomes srcs)
    unsigned char* xq  = (unsigned char*)p;   p += (size_t)NN * IND;    // 6.4MB
    unsigned short* m1b = (unsigned short*)p; p += (size_t)NN * IND * 2; // 12.8MB
    unsigned short* h1b = (unsigned short*)p; p += (size_t)NN * HID * 2; // 25.6MB
    unsigned char* h1q  = (unsigned char*)p;  p += (size_t)NN * HID;     // 12.8MB
    unsigned short* m2b = (unsigned short*)p; p += (size_t)NN * HID * 2; // 25.6MB
    unsigned short* Wp1 = (unsigned short*)p; p += 8 * 4 * 64 * 8 * 2;   // 32KB
    unsigned short* Wp2 = (unsigned short*)p; p += 8 * 8 * 64 * 8 * 2;   // 64KB
    const size_t need_v3 = (size_t)(p - (char*)d_ws);
    const size_t need_csr = ((size_t)3 * NN + 128 + NE) * sizeof(int);

    if (ws_size >= need_v3) {
        prep_kernel<<<CVT_BLKS + PW1_BLKS + PW2_BLKS + 1, 256, 0, stream>>>(
            (const float4*)x, (unsigned*)xq, Wr1, Wl1, Wp1, Wr2, Wl2, Wp2, bktcur);
        binA_kernel<<<NBLK_E, 512, 0, stream>>>(src, dst, bktcur, bins);
        binB_kernel<<<NBKT2, 512, 0, stream>>>(bktcur, bins, cnt, off);
        agg1_kernel<<<NN / 4, 256, 0, stream>>>(xq, (const int*)bins, off, cnt, m1b);
        mfma1_kernel<<<(NN + 63) / 64, 256, 0, stream>>>(x, m1b, Wp1, b1, h1f, h1b, h1q);
        agg2_kernel<<<NN / 4, 256, 0, stream>>>(h1q, (const int*)bins, off, cnt, m2b);
        mfma2_kernel<<<(NN + 63) / 64, 256, 0, stream>>>(h1b, m2b, Wp2, b2, Wout, bout, h2f, out);
    } else if (ws_size >= need_csr) {
        int* cntF   = (int*)d_ws;
        int* offF   = cntF + NN;
        int* curF   = offF + NN;
        int* bsums  = curF + NN;
        int* srcsF  = bsums + 128;
        zero_int_kernel<<<(NN / 4 + 255) / 256, 256, 0, stream>>>((int4*)cntF, NN / 4);
        hist_kernel<<<(NE + 255) / 256, 256, 0, stream>>>(dst, cntF);
        scanA_kernel<<<NSB, 256, 0, stream>>>(cntF, bsums);
        scanB_kernel<<<1, 1, 0, stream>>>(bsums);
        scanC_kernel<<<NSB, 256, 0, stream>>>(cntF, bsums, offF, curF);
        fill_kernel<<<(NE + 255) / 256, 256, 0, stream>>>(src, dst, curF, srcsF);
        agg1f_kernel<<<NN / 4, 256, 0, stream>>>(x, srcsF, offF, cntF, h1f);
        gemm1f_kernel<<<NN / 16, 256, 0, stream>>>(x, Wl1, Wr1, b1, h1f);
        agg2f_kernel<<<NN / 2, 256, 0, stream>>>(h1f, srcsF, offF, cntF, h2f);
        gemm2f_kernel<<<NN / 16, 256, 0, stream>>>(h1f, Wl2, Wr2, b2, Wout, bout, h2f, out);
    }
}

// Round 9
// 216.170 us; speedup vs baseline: 1.3830x; 1.0108x over previous
//
#include <hip/hip_runtime.h>

#define NN 100000
#define IND 64
#define HID 128
#define NE 1600000

// ---- CSR build v3: fixed-capacity 256-node buckets ----
#define BKT2 256
#define NBKT2 ((NN + BKT2 - 1) / BKT2)     // 391 buckets
#define CAP 4992                           // mean 4092 + ~14 sigma
#define EPB 4096
#define NBLK_E ((NE + EPB - 1) / EPB)      // 391 edge chunks

// ---- prep kernel block ranges ----
#define CVT_BLKS (NN * IND / 4 / 256)      // 6250
#define PW1_BLKS 8
#define PW2_BLKS 16

// ---- gather batching ----
#define AGK 4   // nodes per wave
#define AGS 3   // prefetch slots of 8 edges -> covers deg<=24 without residual

// ---- fallback fp32 CSR path ----
#define SCAN_CHUNK 1024
#define NSB ((NN + SCAN_CHUNK - 1) / SCAN_CHUNK)

typedef __attribute__((ext_vector_type(8))) short bf16x8;
typedef __attribute__((ext_vector_type(4))) float f32x4;
typedef __attribute__((ext_vector_type(2))) float f32x2;

static __device__ __forceinline__ unsigned short f2bf(float f) {
    unsigned u = __float_as_uint(f);
    u = (u + 0x7FFFu + ((u >> 16) & 1u)) >> 16;   // RNE
    return (unsigned short)u;
}
static __device__ __forceinline__ unsigned pack2(float a, float b) {
    return (unsigned)f2bf(a) | ((unsigned)f2bf(b) << 16);
}

// ===================== prep: cvt_xq + packW1 + packW2 + zero =====================

static __device__ __forceinline__ void packW_body(const float* __restrict__ Wr,
                                                  const float* __restrict__ Wl,
                                                  int Khalf, int KS, int t,
                                                  unsigned short* __restrict__ Wp) {
    if (t >= 8 * KS * 64) return;
    int l  = t & 63;
    int ks = (t >> 6) % KS;
    int jt = t / (64 * KS);
    int j  = jt * 16 + (l & 15);
    int kb = ks * 32 + (l >> 4) * 8;
    unsigned short v[8];
    #pragma unroll
    for (int i = 0; i < 8; ++i) {
        int k = kb + i;
        float w = (k < Khalf) ? Wr[k * HID + j] : Wl[(k - Khalf) * HID + j];
        v[i] = f2bf(w);
    }
    ushort4 lo, hi;
    lo.x = v[0]; lo.y = v[1]; lo.z = v[2]; lo.w = v[3];
    hi.x = v[4]; hi.y = v[5]; hi.z = v[6]; hi.w = v[7];
    ushort4* d = reinterpret_cast<ushort4*>(Wp + (size_t)t * 8);
    d[0] = lo; d[1] = hi;
}

__global__ __launch_bounds__(256) void prep_kernel(const float4* __restrict__ x,
                                                   unsigned* __restrict__ xq,
                                                   const float* __restrict__ Wr1,
                                                   const float* __restrict__ Wl1,
                                                   unsigned short* __restrict__ Wp1,
                                                   const float* __restrict__ Wr2,
                                                   const float* __restrict__ Wl2,
                                                   unsigned short* __restrict__ Wp2,
                                                   int* __restrict__ bktcur) {
    int blk = blockIdx.x, t = threadIdx.x;
    if (blk < CVT_BLKS) {
        int i = blk * 256 + t;
        float4 v = x[i];
        int u = __builtin_amdgcn_cvt_pk_fp8_f32(v.x, v.y, 0, false);
        u = __builtin_amdgcn_cvt_pk_fp8_f32(v.z, v.w, u, true);
        xq[i] = (unsigned)u;
    } else if (blk < CVT_BLKS + PW1_BLKS) {
        packW_body(Wr1, Wl1, IND, 4, (blk - CVT_BLKS) * 256 + t, Wp1);
    } else if (blk < CVT_BLKS + PW1_BLKS + PW2_BLKS) {
        packW_body(Wr2, Wl2, HID, 8, (blk - CVT_BLKS - PW1_BLKS) * 256 + t, Wp2);
    } else {
        bktcur[t] = 0;
        bktcur[t + 256] = 0;
    }
}

// ===================== CSR build v3 =====================

__global__ __launch_bounds__(512) void binA_kernel(const int* __restrict__ src,
                                                   const int* __restrict__ dst,
                                                   int* __restrict__ bktcur,
                                                   unsigned* __restrict__ bins) {
    __shared__ int hcnt[NBKT2];
    __shared__ int rbase[NBKT2];
    int t = threadIdx.x;
    int e0 = blockIdx.x * EPB;
    int ce = min(EPB, NE - e0);
    for (int i = t; i < NBKT2; i += 512) hcnt[i] = 0;
    __syncthreads();
    for (int i = t; i < ce; i += 512)
        atomicAdd(&hcnt[dst[e0 + i] >> 8], 1);
    __syncthreads();
    for (int i = t; i < NBKT2; i += 512) {
        int c = hcnt[i];
        rbase[i] = c ? atomicAdd(&bktcur[i], c) : 0;
        hcnt[i] = 0;
    }
    __syncthreads();
    for (int i = t; i < ce; i += 512) {
        int d = dst[e0 + i];
        int b = d >> 8;
        int r = atomicAdd(&hcnt[b], 1);
        bins[(size_t)b * CAP + rbase[b] + r] =
            (unsigned)src[e0 + i] | ((unsigned)(d & 255) << 17);
    }
}

__global__ __launch_bounds__(512) void binB_kernel(const int* __restrict__ bktcur,
                                                   unsigned* __restrict__ bins,
                                                   int* __restrict__ cnt,
                                                   int* __restrict__ off) {
    __shared__ unsigned ebuf[CAP];
    __shared__ int ncnt[BKT2];
    __shared__ int nofs[BKT2];
    __shared__ int wtot[4];
    int t = threadIdx.x, lane = t & 63, w = t >> 6;
    int b = blockIdx.x;
    int m = bktcur[b];
    size_t base = (size_t)b * CAP;
    for (int i = t; i < m; i += 512) ebuf[i] = bins[base + i];
    if (t < BKT2) ncnt[t] = 0;
    __syncthreads();
    for (int i = t; i < m; i += 512)
        atomicAdd(&ncnt[ebuf[i] >> 17], 1);
    __syncthreads();
    if (t < BKT2) {
        int v = ncnt[t];
        int incl = v;
        #pragma unroll
        for (int o = 1; o < 64; o <<= 1) {
            int u = __shfl_up(incl, o);
            if (lane >= o) incl += u;
        }
        if (lane == 63) wtot[w] = incl;
        nofs[t] = incl - v;
    }
    __syncthreads();
    if (t < BKT2) {
        int wbase = 0;
        #pragma unroll
        for (int i = 0; i < 4; ++i) if (i < w) wbase += wtot[i];
        int ex = nofs[t] + wbase;
        nofs[t] = ex;
        int node = b * BKT2 + t;
        if (node < NN) { cnt[node] = ncnt[t]; off[node] = (int)base + ex; }
    }
    __syncthreads();
    for (int i = t; i < m; i += 512) {
        unsigned val = ebuf[i];
        int r = atomicAdd(&nofs[val >> 17], 1);
        bins[base + r] = val & 0x1FFFFu;
    }
}

// ===================== fp8 gather means (K-node batched, masked prefetch) =====================

// agg1: 64B rows; 8 lanes/row (uint2), 8 edge-groups, AGK nodes/wave
__global__ __launch_bounds__(256) void agg1_kernel(const unsigned char* __restrict__ xq,
                                                   const int* __restrict__ srcs,
                                                   const int* __restrict__ off,
                                                   const int* __restrict__ cnt,
                                                   unsigned short* __restrict__ m1b) {
    int t = threadIdx.x, w = t >> 6, l = t & 63;
    int ep = l >> 3, doff = (l & 7) * 8;
    int nb = (blockIdx.x * 4 + w) * AGK;
    int deg[AGK], s0[AGK];
    #pragma unroll
    for (int k = 0; k < AGK; ++k) { deg[k] = cnt[nb + k]; s0[k] = off[nb + k]; }
    int si[AGK][AGS];
    #pragma unroll
    for (int k = 0; k < AGK; ++k)
        #pragma unroll
        for (int s = 0; s < AGS; ++s)
            si[k][s] = srcs[s0[k] + ep + s * 8];   // garbage ok if masked below
    uint2 row[AGK][AGS];
    #pragma unroll
    for (int k = 0; k < AGK; ++k)
        #pragma unroll
        for (int s = 0; s < AGS; ++s) {
            if (ep + s * 8 < deg[k])
                row[k][s] = *reinterpret_cast<const uint2*>(
                    xq + (size_t)(unsigned)si[k][s] * IND + doff);
            else
                row[k][s] = make_uint2(0u, 0u);    // fp8 0x00 == 0.0
        }
    #pragma unroll
    for (int k = 0; k < AGK; ++k) {
        float acc[8];
        #pragma unroll
        for (int i = 0; i < 8; ++i) acc[i] = 0.f;
        #pragma unroll
        for (int s = 0; s < AGS; ++s) {
            unsigned wu[2] = {row[k][s].x, row[k][s].y};
            #pragma unroll
            for (int q = 0; q < 2; ++q) {
                f32x2 lo = __builtin_amdgcn_cvt_pk_f32_fp8((int)wu[q], false);
                f32x2 hi = __builtin_amdgcn_cvt_pk_f32_fp8((int)wu[q], true);
                acc[q * 4 + 0] += lo.x; acc[q * 4 + 1] += lo.y;
                acc[q * 4 + 2] += hi.x; acc[q * 4 + 3] += hi.y;
            }
        }
        for (int e = ep + AGS * 8; e < deg[k]; e += 8) {   // rare residual
            int s = srcs[s0[k] + e];
            uint2 u = *reinterpret_cast<const uint2*>(xq + (size_t)s * IND + doff);
            unsigned wu[2] = {u.x, u.y};
            #pragma unroll
            for (int q = 0; q < 2; ++q) {
                f32x2 lo = __builtin_amdgcn_cvt_pk_f32_fp8((int)wu[q], false);
                f32x2 hi = __builtin_amdgcn_cvt_pk_f32_fp8((int)wu[q], true);
                acc[q * 4 + 0] += lo.x; acc[q * 4 + 1] += lo.y;
                acc[q * 4 + 2] += hi.x; acc[q * 4 + 3] += hi.y;
            }
        }
        #pragma unroll
        for (int o = 8; o <= 32; o <<= 1) {
            #pragma unroll
            for (int i = 0; i < 8; ++i) acc[i] += __shfl_xor(acc[i], o);
        }
        if (l < 8) {
            float inv = 1.f / fmaxf((float)deg[k], 1.f);
            uint4 o;
            o.x = pack2(acc[0] * inv, acc[1] * inv);
            o.y = pack2(acc[2] * inv, acc[3] * inv);
            o.z = pack2(acc[4] * inv, acc[5] * inv);
            o.w = pack2(acc[6] * inv, acc[7] * inv);
            *reinterpret_cast<uint4*>(m1b + (size_t)(nb + k) * IND + l * 8) = o;
        }
    }
}

// agg2: 128B rows; 8 lanes/row (uint4), 8 edge-groups, AGK nodes/wave
__global__ __launch_bounds__(256) void agg2_kernel(const unsigned char* __restrict__ h1q,
                                                   const int* __restrict__ srcs,
                                                   const int* __restrict__ off,
                                                   const int* __restrict__ cnt,
                                                   unsigned short* __restrict__ m2b) {
    int t = threadIdx.x, w = t >> 6, l = t & 63;
    int ep = l >> 3, doff = (l & 7) * 16;
    int nb = (blockIdx.x * 4 + w) * AGK;
    int deg[AGK], s0[AGK];
    #pragma unroll
    for (int k = 0; k < AGK; ++k) { deg[k] = cnt[nb + k]; s0[k] = off[nb + k]; }
    int si[AGK][AGS];
    #pragma unroll
    for (int k = 0; k < AGK; ++k)
        #pragma unroll
        for (int s = 0; s < AGS; ++s)
            si[k][s] = srcs[s0[k] + ep + s * 8];
    uint4 row[AGK][AGS];
    #pragma unroll
    for (int k = 0; k < AGK; ++k)
        #pragma unroll
        for (int s = 0; s < AGS; ++s) {
            if (ep + s * 8 < deg[k])
                row[k][s] = *reinterpret_cast<const uint4*>(
                    h1q + (size_t)(unsigned)si[k][s] * HID + doff);
            else
                row[k][s] = make_uint4(0u, 0u, 0u, 0u);
        }
    #pragma unroll
    for (int k = 0; k < AGK; ++k) {
        float acc[16];
        #pragma unroll
        for (int i = 0; i < 16; ++i) acc[i] = 0.f;
        #pragma unroll
        for (int s = 0; s < AGS; ++s) {
            unsigned wu[4] = {row[k][s].x, row[k][s].y, row[k][s].z, row[k][s].w};
            #pragma unroll
            for (int q = 0; q < 4; ++q) {
                f32x2 lo = __builtin_amdgcn_cvt_pk_f32_fp8((int)wu[q], false);
                f32x2 hi = __builtin_amdgcn_cvt_pk_f32_fp8((int)wu[q], true);
                acc[q * 4 + 0] += lo.x; acc[q * 4 + 1] += lo.y;
                acc[q * 4 + 2] += hi.x; acc[q * 4 + 3] += hi.y;
            }
        }
        for (int e = ep + AGS * 8; e < deg[k]; e += 8) {   // rare residual
            int s = srcs[s0[k] + e];
            uint4 u = *reinterpret_cast<const uint4*>(h1q + (size_t)s * HID + doff);
            unsigned wu[4] = {u.x, u.y, u.z, u.w};
            #pragma unroll
            for (int q = 0; q < 4; ++q) {
                f32x2 lo = __builtin_amdgcn_cvt_pk_f32_fp8((int)wu[q], false);
                f32x2 hi = __builtin_amdgcn_cvt_pk_f32_fp8((int)wu[q], true);
                acc[q * 4 + 0] += lo.x; acc[q * 4 + 1] += lo.y;
                acc[q * 4 + 2] += hi.x; acc[q * 4 + 3] += hi.y;
            }
        }
        #pragma unroll
        for (int o = 8; o <= 32; o <<= 1) {
            #pragma unroll
            for (int i = 0; i < 16; ++i) acc[i] += __shfl_xor(acc[i], o);
        }
        if (l < 8) {
            float inv = 1.f / fmaxf((float)deg[k], 1.f);
            uint4 o1, o2;
            o1.x = pack2(acc[0] * inv,  acc[1] * inv);
            o1.y = pack2(acc[2] * inv,  acc[3] * inv);
            o1.z = pack2(acc[4] * inv,  acc[5] * inv);
            o1.w = pack2(acc[6] * inv,  acc[7] * inv);
            o2.x = pack2(acc[8] * inv,  acc[9] * inv);
            o2.y = pack2(acc[10] * inv, acc[11] * inv);
            o2.z = pack2(acc[12] * inv, acc[13] * inv);
            o2.w = pack2(acc[14] * inv, acc[15] * inv);
            unsigned short* dstp = m2b + (size_t)(nb + k) * HID + l * 16;
            *reinterpret_cast<uint4*>(dstp) = o1;
            *reinterpret_cast<uint4*>(dstp + 8) = o2;
        }
    }
}

// ===================== MFMA dense layers =====================

__global__ __launch_bounds__(256) void mfma1_kernel(const float* __restrict__ x,
                                                    const unsigned short* __restrict__ m1b,
                                                    const unsigned short* __restrict__ Wp,
                                                    const float* __restrict__ b,
                                                    float* __restrict__ h1f,
                                                    unsigned short* __restrict__ h1b,
                                                    unsigned char* __restrict__ h1q) {
    int t = threadIdx.x, w = t >> 6, l = t & 63;
    int row0 = blockIdx.x * 64 + w * 16;
    int arow = row0 + (l & 15); if (arow > NN - 1) arow = NN - 1;
    int kcol = (l >> 4) * 8;
    f32x4 acc[8];
    #pragma unroll
    for (int jt = 0; jt < 8; ++jt) { acc[jt][0] = 0.f; acc[jt][1] = 0.f; acc[jt][2] = 0.f; acc[jt][3] = 0.f; }
    #pragma unroll
    for (int ks = 0; ks < 4; ++ks) {
        bf16x8 a;
        int c = (ks & 1) * 32 + kcol;
        if (ks < 2) {
            const float* xr = x + (size_t)arow * IND + c;
            float4 f0 = *reinterpret_cast<const float4*>(xr);
            float4 f1 = *reinterpret_cast<const float4*>(xr + 4);
            a[0] = (short)f2bf(f0.x); a[1] = (short)f2bf(f0.y);
            a[2] = (short)f2bf(f0.z); a[3] = (short)f2bf(f0.w);
            a[4] = (short)f2bf(f1.x); a[5] = (short)f2bf(f1.y);
            a[6] = (short)f2bf(f1.z); a[7] = (short)f2bf(f1.w);
        } else {
            a = *reinterpret_cast<const bf16x8*>(m1b + (size_t)arow * IND + c);
        }
        #pragma unroll
        for (int jt = 0; jt < 8; ++jt) {
            bf16x8 bb = *reinterpret_cast<const bf16x8*>(Wp + ((size_t)(jt * 4 + ks) * 64 + l) * 8);
            acc[jt] = __builtin_amdgcn_mfma_f32_16x16x32_bf16(a, bb, acc[jt], 0, 0, 0);
        }
    }
    int rbase = row0 + (l >> 4) * 4;
    #pragma unroll
    for (int jt = 0; jt < 8; ++jt) {
        int col = jt * 16 + (l & 15);
        float bias = b[col];
        #pragma unroll
        for (int r = 0; r < 4; ++r) {
            int row = rbase + r;
            if (row < NN) {
                float v = fmaxf(acc[jt][r] + bias, 0.f);
                h1f[(size_t)row * HID + col] = v;
                h1b[(size_t)row * HID + col] = f2bf(v);
                unsigned q8 = (unsigned)__builtin_amdgcn_cvt_pk_fp8_f32(v, 0.f, 0, false) & 0xFFu;
                h1q[(size_t)row * HID + col] = (unsigned char)q8;
            }
        }
    }
}

__global__ __launch_bounds__(256) void mfma2_kernel(const unsigned short* __restrict__ h1b,
                                                    const unsigned short* __restrict__ m2b,
                                                    const unsigned short* __restrict__ Wp,
                                                    const float* __restrict__ b,
                                                    const float* __restrict__ Wout,
                                                    const float* __restrict__ bout,
                                                    float* __restrict__ h2f,
                                                    float* __restrict__ out) {
    int t = threadIdx.x, w = t >> 6, l = t & 63;
    int row0 = blockIdx.x * 64 + w * 16;
    int arow = row0 + (l & 15); if (arow > NN - 1) arow = NN - 1;
    int kcol = (l >> 4) * 8;
    f32x4 acc[8];
    #pragma unroll
    for (int jt = 0; jt < 8; ++jt) { acc[jt][0] = 0.f; acc[jt][1] = 0.f; acc[jt][2] = 0.f; acc[jt][3] = 0.f; }
    #pragma unroll
    for (int ks = 0; ks < 8; ++ks) {
        const unsigned short* A = (ks < 4) ? h1b : m2b;
        int c = (ks & 3) * 32 + kcol;
        bf16x8 a = *reinterpret_cast<const bf16x8*>(A + (size_t)arow * HID + c);
        #pragma unroll
        for (int jt = 0; jt < 8; ++jt) {
            bf16x8 bb = *reinterpret_cast<const bf16x8*>(Wp + ((size_t)(jt * 8 + ks) * 64 + l) * 8);
            acc[jt] = __builtin_amdgcn_mfma_f32_16x16x32_bf16(a, bb, acc[jt], 0, 0, 0);
        }
    }
    int rbase = row0 + (l >> 4) * 4;
    float hs0 = 0.f, hs1 = 0.f, hs2 = 0.f, hs3 = 0.f;
    #pragma unroll
    for (int jt = 0; jt < 8; ++jt) {
        int col = jt * 16 + (l & 15);
        float bias = b[col];
        float wo = Wout[col];
        #pragma unroll
        for (int r = 0; r < 4; ++r) {
            int row = rbase + r;
            float v = acc[jt][r] + bias;
            if (row < NN) h2f[(size_t)row * HID + col] = v;
            if (r == 0) hs0 += v * wo;
            else if (r == 1) hs1 += v * wo;
            else if (r == 2) hs2 += v * wo;
            else hs3 += v * wo;
        }
    }
    #pragma unroll
    for (int o = 1; o < 16; o <<= 1) {
        hs0 += __shfl_xor(hs0, o);
        hs1 += __shfl_xor(hs1, o);
        hs2 += __shfl_xor(hs2, o);
        hs3 += __shfl_xor(hs3, o);
    }
    if ((l & 15) == 0) {
        float bo = bout[0];
        if (rbase + 0 < NN) out[rbase + 0] = hs0 + bo;
        if (rbase + 1 < NN) out[rbase + 1] = hs1 + bo;
        if (rbase + 2 < NN) out[rbase + 2] = hs2 + bo;
        if (rbase + 3 < NN) out[rbase + 3] = hs3 + bo;
    }
}

// ===================== fp32 CSR fallback (round-2) =====================

__global__ __launch_bounds__(256) void zero_int_kernel(int4* __restrict__ p, int n4) {
    int i = blockIdx.x * 256 + threadIdx.x;
    if (i < n4) p[i] = make_int4(0, 0, 0, 0);
}

__global__ __launch_bounds__(256) void hist_kernel(const int* __restrict__ dst,
                                                   int* __restrict__ cnt) {
    int e = blockIdx.x * 256 + threadIdx.x;
    if (e < NE) atomicAdd(&cnt[dst[e]], 1);
}

__global__ __launch_bounds__(256) void scanA_kernel(const int* __restrict__ cnt,
                                                    int* __restrict__ bsums) {
    int b = blockIdx.x, t = threadIdx.x;
    int base = b * SCAN_CHUNK + t * 4;
    int s = 0;
    #pragma unroll
    for (int k = 0; k < 4; ++k) { int i = base + k; if (i < NN) s += cnt[i]; }
    #pragma unroll
    for (int o = 32; o > 0; o >>= 1) s += __shfl_down(s, o);
    __shared__ int wsum[4];
    if ((t & 63) == 0) wsum[t >> 6] = s;
    __syncthreads();
    if (t == 0) bsums[b] = wsum[0] + wsum[1] + wsum[2] + wsum[3];
}

__global__ void scanB_kernel(int* __restrict__ bsums) {
    int acc = 0;
    for (int i = 0; i < NSB; ++i) { int v = bsums[i]; bsums[i] = acc; acc += v; }
}

__global__ __launch_bounds__(256) void scanC_kernel(const int* __restrict__ cnt,
                                                    const int* __restrict__ bsums,
                                                    int* __restrict__ off,
                                                    int* __restrict__ cur) {
    int b = blockIdx.x, t = threadIdx.x;
    int lane = t & 63, w = t >> 6;
    int base = b * SCAN_CHUNK + t * 4;
    int v[4]; int s = 0;
    #pragma unroll
    for (int k = 0; k < 4; ++k) {
        int i = base + k;
        v[k] = (i < NN) ? cnt[i] : 0;
        s += v[k];
    }
    int inc = s;
    #pragma unroll
    for (int o = 1; o < 64; o <<= 1) {
        int xv = __shfl_up(inc, o);
        if (lane >= o) inc += xv;
    }
    __shared__ int wsum[4];
    if (lane == 63) wsum[w] = inc;
    __syncthreads();
    int wbase = 0;
    for (int i = 0; i < w; ++i) wbase += wsum[i];
    int ex = bsums[b] + wbase + (inc - s);
    #pragma unroll
    for (int k = 0; k < 4; ++k) {
        int i = base + k;
        if (i < NN) { off[i] = ex; cur[i] = ex; }
        ex += v[k];
    }
}

__global__ __launch_bounds__(256) void fill_kernel(const int* __restrict__ src,
                                                   const int* __restrict__ dst,
                                                   int* __restrict__ cur,
                                                   int* __restrict__ srcs) {
    int e = blockIdx.x * 256 + threadIdx.x;
    if (e < NE) {
        int p = atomicAdd(&cur[dst[e]], 1);
        srcs[p] = src[e];
    }
}

__global__ __launch_bounds__(256) void agg1f_kernel(const float* __restrict__ x,
                                                    const int* __restrict__ srcs,
                                                    const int* __restrict__ off,
                                                    const int* __restrict__ cnt,
                                                    float* __restrict__ mean1) {
    int t = threadIdx.x;
    int n = blockIdx.x * 4 + (t >> 6);
    int d = t & 63;
    int s0 = off[n], deg = cnt[n];
    float acc = 0.f;
    for (int e = 0; e < deg; ++e) acc += x[(size_t)srcs[s0 + e] * IND + d];
    mean1[(size_t)n * HID + d] = acc / fmaxf((float)deg, 1.f);
}

__global__ __launch_bounds__(256) void agg2f_kernel(const float* __restrict__ h1,
                                                    const int* __restrict__ srcs,
                                                    const int* __restrict__ off,
                                                    const int* __restrict__ cnt,
                                                    float* __restrict__ mean2) {
    int t = threadIdx.x;
    int n = blockIdx.x * 2 + (t >> 7);
    int d = t & 127;
    int s0 = off[n], deg = cnt[n];
    float acc = 0.f;
    for (int e = 0; e < deg; ++e) acc += h1[(size_t)srcs[s0 + e] * HID + d];
    mean2[(size_t)n * HID + d] = acc / fmaxf((float)deg, 1.f);
}

__global__ __launch_bounds__(256) void gemm1f_kernel(const float* __restrict__ x,
                                                     const float* __restrict__ Wl,
                                                     const float* __restrict__ Wr,
                                                     const float* __restrict__ b,
                                                     float* __restrict__ h1) {
    __shared__ float in[16][128];
    int t = threadIdx.x;
    int node0 = blockIdx.x * 16;
    for (int idx = t; idx < 16 * 128; idx += 256) {
        int r = idx >> 7, c = idx & 127;
        in[r][c] = (c < IND) ? x[(size_t)(node0 + r) * IND + c]
                             : h1[(size_t)(node0 + r) * HID + (c - IND)];
    }
    __syncthreads();
    int j = t & 127, g = t >> 7;
    float acc[8];
    float bj = b[j];
    #pragma unroll
    for (int q = 0; q < 8; ++q) acc[q] = bj;
    for (int k = 0; k < 128; ++k) {
        float wv = (k < IND) ? Wr[k * HID + j] : Wl[(k - IND) * HID + j];
        #pragma unroll
        for (int q = 0; q < 8; ++q) acc[q] += in[g * 8 + q][k] * wv;
    }
    #pragma unroll
    for (int q = 0; q < 8; ++q)
        h1[(size_t)(node0 + g * 8 + q) * HID + j] = fmaxf(acc[q], 0.f);
}

__global__ __launch_bounds__(256) void gemm2f_kernel(const float* __restrict__ h1,
                                                     const float* __restrict__ Wl,
                                                     const float* __restrict__ Wr,
                                                     const float* __restrict__ b,
                                                     const float* __restrict__ Wout,
                                                     const float* __restrict__ bout,
                                                     float* __restrict__ h2,
                                                     float* __restrict__ out) {
    __shared__ float in[16][256];
    __shared__ float part[4][8];
    int t = threadIdx.x;
    int node0 = blockIdx.x * 16;
    for (int idx = t; idx < 16 * 256; idx += 256) {
        int r = idx >> 8, c = idx & 255;
        in[r][c] = (c < HID) ? h1[(size_t)(node0 + r) * HID + c]
                             : h2[(size_t)(node0 + r) * HID + (c - HID)];
    }
    __syncthreads();
    int j = t & 127, g = t >> 7, lane = t & 63, w = t >> 6;
    float acc[8];
    float bj = b[j];
    #pragma unroll
    for (int q = 0; q < 8; ++q) acc[q] = bj;
    for (int k = 0; k < 256; ++k) {
        float wv = (k < HID) ? Wr[k * HID + j] : Wl[(k - HID) * HID + j];
        #pragma unroll
        for (int q = 0; q < 8; ++q) acc[q] += in[g * 8 + q][k] * wv;
    }
    float wo = Wout[j];
    #pragma unroll
    for (int q = 0; q < 8; ++q)
        h2[(size_t)(node0 + g * 8 + q) * HID + j] = acc[q];
    #pragma unroll
    for (int q = 0; q < 8; ++q) {
        float v = acc[q] * wo;
        #pragma unroll
        for (int o = 32; o > 0; o >>= 1) v += __shfl_down(v, o);
        if (lane == 0) part[w][q] = v;
    }
    __syncthreads();
    if (t < 16) {
        int gg = t >> 3, q = t & 7;
        out[node0 + t] = part[2 * gg][q] + part[2 * gg + 1][q] + bout[0];
    }
}

// ============================ launch ============================

extern "C" void kernel_launch(void* const* d_in, const int* in_sizes, int n_in,
                              void* d_out, int out_size, void* d_ws, size_t ws_size,
                              hipStream_t stream) {
    const float* x    = (const float*)d_in[0];
    const int*   eidx = (const int*)d_in[1];
    const int*   src  = eidx;
    const int*   dst  = eidx + NE;
    const float* Wl1  = (const float*)d_in[2];
    const float* Wr1  = (const float*)d_in[3];
    const float* b1   = (const float*)d_in[4];
    const float* Wl2  = (const float*)d_in[5];
    const float* Wr2  = (const float*)d_in[6];
    const float* b2   = (const float*)d_in[7];
    const float* Wout = (const float*)d_in[8];
    const float* bout = (const float*)d_in[9];

    float* out = (float*)d_out;
    float* h1f = out + NN;
    float* h2f = h1f + (size_t)NN * HID;

    // ---- workspace layout (~92 MB) ----
    char* p = (char*)d_ws;
    int* cnt        = (int*)p;            p += (size_t)NN * 4;
    int* off        = (int*)p;            p += (size_t)NN * 4;
    int* bktcur     = (int*)p;            p += 512 * 4;
    unsigned* bins  = (unsigned*)p;       p += (size_t)NBKT2 * CAP * 4; // 7.8MB (becomes srcs)
    unsigned char* xq  = (unsigned char*)p;   p += (size_t)NN * IND;    // 6.4MB
    unsigned short* m1b = (unsigned short*)p; p += (size_t)NN * IND * 2; // 12.8MB
    unsigned short* h1b = (unsigned short*)p; p += (size_t)NN * HID * 2; // 25.6MB
    unsigned char* h1q  = (unsigned char*)p;  p += (size_t)NN * HID;     // 12.8MB
    unsigned short* m2b = (unsigned short*)p; p += (size_t)NN * HID * 2; // 25.6MB
    unsigned short* Wp1 = (unsigned short*)p; p += 8 * 4 * 64 * 8 * 2;   // 32KB
    unsigned short* Wp2 = (unsigned short*)p; p += 8 * 8 * 64 * 8 * 2;   // 64KB
    const size_t need_v3 = (size_t)(p - (char*)d_ws);
    const size_t need_csr = ((size_t)3 * NN + 128 + NE) * sizeof(int);

    if (ws_size >= need_v3) {
        prep_kernel<<<CVT_BLKS + PW1_BLKS + PW2_BLKS + 1, 256, 0, stream>>>(
            (const float4*)x, (unsigned*)xq, Wr1, Wl1, Wp1, Wr2, Wl2, Wp2, bktcur);
        binA_kernel<<<NBLK_E, 512, 0, stream>>>(src, dst, bktcur, bins);
        binB_kernel<<<NBKT2, 512, 0, stream>>>(bktcur, bins, cnt, off);
        agg1_kernel<<<NN / 16, 256, 0, stream>>>(xq, (const int*)bins, off, cnt, m1b);
        mfma1_kernel<<<(NN + 63) / 64, 256, 0, stream>>>(x, m1b, Wp1, b1, h1f, h1b, h1q);
        agg2_kernel<<<NN / 16, 256, 0, stream>>>(h1q, (const int*)bins, off, cnt, m2b);
        mfma2_kernel<<<(NN + 63) / 64, 256, 0, stream>>>(h1b, m2b, Wp2, b2, Wout, bout, h2f, out);
    } else if (ws_size >= need_csr) {
        int* cntF   = (int*)d_ws;
        int* offF   = cntF + NN;
        int* curF   = offF + NN;
        int* bsums  = curF + NN;
        int* srcsF  = bsums + 128;
        zero_int_kernel<<<(NN / 4 + 255) / 256, 256, 0, stream>>>((int4*)cntF, NN / 4);
        hist_kernel<<<(NE + 255) / 256, 256, 0, stream>>>(dst, cntF);
        scanA_kernel<<<NSB, 256, 0, stream>>>(cntF, bsums);
        scanB_kernel<<<1, 1, 0, stream>>>(bsums);
        scanC_kernel<<<NSB, 256, 0, stream>>>(cntF, bsums, offF, curF);
        fill_kernel<<<(NE + 255) / 256, 256, 0, stream>>>(src, dst, curF, srcsF);
        agg1f_kernel<<<NN / 4, 256, 0, stream>>>(x, srcsF, offF, cntF, h1f);
        gemm1f_kernel<<<NN / 16, 256, 0, stream>>>(x, Wl1, Wr1, b1, h1f);
        agg2f_kernel<<<NN / 2, 256, 0, stream>>>(h1f, srcsF, offF, cntF, h2f);
        gemm2f_kernel<<<NN / 16, 256, 0, stream>>>(h1f, Wl2, Wr2, b2, Wout, bout, h2f, out);
    }
}

// Round 10
// 213.489 us; speedup vs baseline: 1.4004x; 1.0126x over previous
//
#include <hip/hip_runtime.h>

#define NN 100000
#define IND 64
#define HID 128
#define NE 1600000

// ---- CSR build v3: fixed-capacity 256-node buckets ----
#define BKT2 256
#define NBKT2 ((NN + BKT2 - 1) / BKT2)     // 391 buckets
#define CAP 4992                           // mean 4092 + ~14 sigma
#define EPB 4096
#define NBLK_E ((NE + EPB - 1) / EPB)      // 391 edge chunks

// ---- prep kernel block ranges ----
#define CVT_BLKS (NN * IND / 4 / 256)      // 6250
#define PW1_BLKS 8
#define PW2_BLKS 16

// ---- fallback fp32 CSR path ----
#define SCAN_CHUNK 1024
#define NSB ((NN + SCAN_CHUNK - 1) / SCAN_CHUNK)

typedef __attribute__((ext_vector_type(8))) short bf16x8;
typedef __attribute__((ext_vector_type(4))) float f32x4;
typedef __attribute__((ext_vector_type(2))) float f32x2;

static __device__ __forceinline__ unsigned short f2bf(float f) {
    unsigned u = __float_as_uint(f);
    u = (u + 0x7FFFu + ((u >> 16) & 1u)) >> 16;   // RNE
    return (unsigned short)u;
}
static __device__ __forceinline__ unsigned pack2(float a, float b) {
    return (unsigned)f2bf(a) | ((unsigned)f2bf(b) << 16);
}

// ===================== prep: cvt_xq + packW1 + packW2 + zero =====================

static __device__ __forceinline__ void packW_body(const float* __restrict__ Wr,
                                                  const float* __restrict__ Wl,
                                                  int Khalf, int KS, int t,
                                                  unsigned short* __restrict__ Wp) {
    if (t >= 8 * KS * 64) return;
    int l  = t & 63;
    int ks = (t >> 6) % KS;
    int jt = t / (64 * KS);
    int j  = jt * 16 + (l & 15);
    int kb = ks * 32 + (l >> 4) * 8;
    unsigned short v[8];
    #pragma unroll
    for (int i = 0; i < 8; ++i) {
        int k = kb + i;
        float w = (k < Khalf) ? Wr[k * HID + j] : Wl[(k - Khalf) * HID + j];
        v[i] = f2bf(w);
    }
    ushort4 lo, hi;
    lo.x = v[0]; lo.y = v[1]; lo.z = v[2]; lo.w = v[3];
    hi.x = v[4]; hi.y = v[5]; hi.z = v[6]; hi.w = v[7];
    ushort4* d = reinterpret_cast<ushort4*>(Wp + (size_t)t * 8);
    d[0] = lo; d[1] = hi;
}

__global__ __launch_bounds__(256) void prep_kernel(const float4* __restrict__ x,
                                                   unsigned* __restrict__ xq,
                                                   const float* __restrict__ Wr1,
                                                   const float* __restrict__ Wl1,
                                                   unsigned short* __restrict__ Wp1,
                                                   const float* __restrict__ Wr2,
                                                   const float* __restrict__ Wl2,
                                                   unsigned short* __restrict__ Wp2,
                                                   int* __restrict__ bktcur) {
    int blk = blockIdx.x, t = threadIdx.x;
    if (blk < CVT_BLKS) {
        int i = blk * 256 + t;
        float4 v = x[i];
        int u = __builtin_amdgcn_cvt_pk_fp8_f32(v.x, v.y, 0, false);
        u = __builtin_amdgcn_cvt_pk_fp8_f32(v.z, v.w, u, true);
        xq[i] = (unsigned)u;
    } else if (blk < CVT_BLKS + PW1_BLKS) {
        packW_body(Wr1, Wl1, IND, 4, (blk - CVT_BLKS) * 256 + t, Wp1);
    } else if (blk < CVT_BLKS + PW1_BLKS + PW2_BLKS) {
        packW_body(Wr2, Wl2, HID, 8, (blk - CVT_BLKS - PW1_BLKS) * 256 + t, Wp2);
    } else {
        bktcur[t] = 0;
        bktcur[t + 256] = 0;
    }
}

// ===================== CSR build v3 =====================

__global__ __launch_bounds__(512) void binA_kernel(const int* __restrict__ src,
                                                   const int* __restrict__ dst,
                                                   int* __restrict__ bktcur,
                                                   unsigned* __restrict__ bins) {
    __shared__ int hcnt[NBKT2];
    __shared__ int rbase[NBKT2];
    int t = threadIdx.x;
    int e0 = blockIdx.x * EPB;
    int ce = min(EPB, NE - e0);
    for (int i = t; i < NBKT2; i += 512) hcnt[i] = 0;
    __syncthreads();
    for (int i = t; i < ce; i += 512)
        atomicAdd(&hcnt[dst[e0 + i] >> 8], 1);
    __syncthreads();
    for (int i = t; i < NBKT2; i += 512) {
        int c = hcnt[i];
        rbase[i] = c ? atomicAdd(&bktcur[i], c) : 0;
        hcnt[i] = 0;
    }
    __syncthreads();
    for (int i = t; i < ce; i += 512) {
        int d = dst[e0 + i];
        int b = d >> 8;
        int r = atomicAdd(&hcnt[b], 1);
        bins[(size_t)b * CAP + rbase[b] + r] =
            (unsigned)src[e0 + i] | ((unsigned)(d & 255) << 17);
    }
}

__global__ __launch_bounds__(512) void binB_kernel(const int* __restrict__ bktcur,
                                                   unsigned* __restrict__ bins,
                                                   int* __restrict__ cnt,
                                                   int* __restrict__ off) {
    __shared__ unsigned ebuf[CAP];
    __shared__ int ncnt[BKT2];
    __shared__ int nofs[BKT2];
    __shared__ int wtot[4];
    int t = threadIdx.x, lane = t & 63, w = t >> 6;
    int b = blockIdx.x;
    int m = bktcur[b];
    size_t base = (size_t)b * CAP;
    for (int i = t; i < m; i += 512) ebuf[i] = bins[base + i];
    if (t < BKT2) ncnt[t] = 0;
    __syncthreads();
    for (int i = t; i < m; i += 512)
        atomicAdd(&ncnt[ebuf[i] >> 17], 1);
    __syncthreads();
    if (t < BKT2) {
        int v = ncnt[t];
        int incl = v;
        #pragma unroll
        for (int o = 1; o < 64; o <<= 1) {
            int u = __shfl_up(incl, o);
            if (lane >= o) incl += u;
        }
        if (lane == 63) wtot[w] = incl;
        nofs[t] = incl - v;
    }
    __syncthreads();
    if (t < BKT2) {
        int wbase = 0;
        #pragma unroll
        for (int i = 0; i < 4; ++i) if (i < w) wbase += wtot[i];
        int ex = nofs[t] + wbase;
        nofs[t] = ex;
        int node = b * BKT2 + t;
        if (node < NN) { cnt[node] = ncnt[t]; off[node] = (int)base + ex; }
    }
    __syncthreads();
    for (int i = t; i < m; i += 512) {
        unsigned val = ebuf[i];
        int r = atomicAdd(&nofs[val >> 17], 1);
        bins[base + r] = val & 0x1FFFFu;
    }
}

// ===================== fp8 gather means (16 lanes/row, instruction-balanced) =====================

// agg1: 64B rows; 16 lanes/row (uint = 4 dims/lane), 4-edge parallel
__global__ __launch_bounds__(256) void agg1_kernel(const unsigned char* __restrict__ xq,
                                                   const int* __restrict__ srcs,
                                                   const int* __restrict__ off,
                                                   const int* __restrict__ cnt,
                                                   unsigned short* __restrict__ m1b) {
    int t = threadIdx.x;
    int n = blockIdx.x * 4 + (t >> 6);
    int l = t & 63, g = l >> 4, doff = (l & 15) * 4;
    int s0 = off[n], deg = cnt[n];
    float a0 = 0.f, a1 = 0.f, a2 = 0.f, a3 = 0.f;
    int e = g;
    for (; e + 4 < deg; e += 8) {
        int sA = srcs[s0 + e], sB = srcs[s0 + e + 4];
        unsigned uA = *reinterpret_cast<const unsigned*>(xq + (size_t)sA * IND + doff);
        unsigned uB = *reinterpret_cast<const unsigned*>(xq + (size_t)sB * IND + doff);
        f32x2 lA = __builtin_amdgcn_cvt_pk_f32_fp8((int)uA, false);
        f32x2 hA = __builtin_amdgcn_cvt_pk_f32_fp8((int)uA, true);
        f32x2 lB = __builtin_amdgcn_cvt_pk_f32_fp8((int)uB, false);
        f32x2 hB = __builtin_amdgcn_cvt_pk_f32_fp8((int)uB, true);
        a0 += lA.x + lB.x; a1 += lA.y + lB.y;
        a2 += hA.x + hB.x; a3 += hA.y + hB.y;
    }
    for (; e < deg; e += 4) {
        int s = srcs[s0 + e];
        unsigned u = *reinterpret_cast<const unsigned*>(xq + (size_t)s * IND + doff);
        f32x2 lo = __builtin_amdgcn_cvt_pk_f32_fp8((int)u, false);
        f32x2 hi = __builtin_amdgcn_cvt_pk_f32_fp8((int)u, true);
        a0 += lo.x; a1 += lo.y; a2 += hi.x; a3 += hi.y;
    }
    a0 += __shfl_xor(a0, 16); a1 += __shfl_xor(a1, 16);
    a2 += __shfl_xor(a2, 16); a3 += __shfl_xor(a3, 16);
    a0 += __shfl_xor(a0, 32); a1 += __shfl_xor(a1, 32);
    a2 += __shfl_xor(a2, 32); a3 += __shfl_xor(a3, 32);
    if (l < 16) {
        float inv = 1.f / fmaxf((float)deg, 1.f);
        uint2 o;
        o.x = pack2(a0 * inv, a1 * inv);
        o.y = pack2(a2 * inv, a3 * inv);
        *reinterpret_cast<uint2*>(m1b + (size_t)n * IND + doff) = o;
    }
}

// agg2: 128B rows; 16 lanes/row (uint2 = 8 dims/lane), 4-edge parallel
__global__ __launch_bounds__(256) void agg2_kernel(const unsigned char* __restrict__ h1q,
                                                   const int* __restrict__ srcs,
                                                   const int* __restrict__ off,
                                                   const int* __restrict__ cnt,
                                                   unsigned short* __restrict__ m2b) {
    int t = threadIdx.x;
    int n = blockIdx.x * 4 + (t >> 6);
    int l = t & 63, g = l >> 4, doff = (l & 15) * 8;
    int s0 = off[n], deg = cnt[n];
    float acc[8];
    #pragma unroll
    for (int i = 0; i < 8; ++i) acc[i] = 0.f;
    int e = g;
    for (; e + 4 < deg; e += 8) {
        int sA = srcs[s0 + e], sB = srcs[s0 + e + 4];
        uint2 uA = *reinterpret_cast<const uint2*>(h1q + (size_t)sA * HID + doff);
        uint2 uB = *reinterpret_cast<const uint2*>(h1q + (size_t)sB * HID + doff);
        unsigned wa[2] = {uA.x, uA.y};
        unsigned wb[2] = {uB.x, uB.y};
        #pragma unroll
        for (int q = 0; q < 2; ++q) {
            f32x2 la = __builtin_amdgcn_cvt_pk_f32_fp8((int)wa[q], false);
            f32x2 ha = __builtin_amdgcn_cvt_pk_f32_fp8((int)wa[q], true);
            f32x2 lb = __builtin_amdgcn_cvt_pk_f32_fp8((int)wb[q], false);
            f32x2 hb = __builtin_amdgcn_cvt_pk_f32_fp8((int)wb[q], true);
            acc[q * 4 + 0] += la.x + lb.x;
            acc[q * 4 + 1] += la.y + lb.y;
            acc[q * 4 + 2] += ha.x + hb.x;
            acc[q * 4 + 3] += ha.y + hb.y;
        }
    }
    for (; e < deg; e += 4) {
        int s = srcs[s0 + e];
        uint2 u = *reinterpret_cast<const uint2*>(h1q + (size_t)s * HID + doff);
        unsigned wu[2] = {u.x, u.y};
        #pragma unroll
        for (int q = 0; q < 2; ++q) {
            f32x2 lo = __builtin_amdgcn_cvt_pk_f32_fp8((int)wu[q], false);
            f32x2 hi = __builtin_amdgcn_cvt_pk_f32_fp8((int)wu[q], true);
            acc[q * 4 + 0] += lo.x; acc[q * 4 + 1] += lo.y;
            acc[q * 4 + 2] += hi.x; acc[q * 4 + 3] += hi.y;
        }
    }
    #pragma unroll
    for (int o = 16; o <= 32; o <<= 1) {
        #pragma unroll
        for (int i = 0; i < 8; ++i) acc[i] += __shfl_xor(acc[i], o);
    }
    if (l < 16) {
        float inv = 1.f / fmaxf((float)deg, 1.f);
        uint4 o;
        o.x = pack2(acc[0] * inv, acc[1] * inv);
        o.y = pack2(acc[2] * inv, acc[3] * inv);
        o.z = pack2(acc[4] * inv, acc[5] * inv);
        o.w = pack2(acc[6] * inv, acc[7] * inv);
        *reinterpret_cast<uint4*>(m2b + (size_t)n * HID + doff) = o;
    }
}

// ===================== MFMA dense layers =====================

__global__ __launch_bounds__(256) void mfma1_kernel(const float* __restrict__ x,
                                                    const unsigned short* __restrict__ m1b,
                                                    const unsigned short* __restrict__ Wp,
                                                    const float* __restrict__ b,
                                                    float* __restrict__ h1f,
                                                    unsigned short* __restrict__ h1b,
                                                    unsigned char* __restrict__ h1q) {
    int t = threadIdx.x, w = t >> 6, l = t & 63;
    int row0 = blockIdx.x * 64 + w * 16;
    int arow = row0 + (l & 15); if (arow > NN - 1) arow = NN - 1;
    int kcol = (l >> 4) * 8;
    f32x4 acc[8];
    #pragma unroll
    for (int jt = 0; jt < 8; ++jt) { acc[jt][0] = 0.f; acc[jt][1] = 0.f; acc[jt][2] = 0.f; acc[jt][3] = 0.f; }
    #pragma unroll
    for (int ks = 0; ks < 4; ++ks) {
        bf16x8 a;
        int c = (ks & 1) * 32 + kcol;
        if (ks < 2) {
            const float* xr = x + (size_t)arow * IND + c;
            float4 f0 = *reinterpret_cast<const float4*>(xr);
            float4 f1 = *reinterpret_cast<const float4*>(xr + 4);
            a[0] = (short)f2bf(f0.x); a[1] = (short)f2bf(f0.y);
            a[2] = (short)f2bf(f0.z); a[3] = (short)f2bf(f0.w);
            a[4] = (short)f2bf(f1.x); a[5] = (short)f2bf(f1.y);
            a[6] = (short)f2bf(f1.z); a[7] = (short)f2bf(f1.w);
        } else {
            a = *reinterpret_cast<const bf16x8*>(m1b + (size_t)arow * IND + c);
        }
        #pragma unroll
        for (int jt = 0; jt < 8; ++jt) {
            bf16x8 bb = *reinterpret_cast<const bf16x8*>(Wp + ((size_t)(jt * 4 + ks) * 64 + l) * 8);
            acc[jt] = __builtin_amdgcn_mfma_f32_16x16x32_bf16(a, bb, acc[jt], 0, 0, 0);
        }
    }
    int rbase = row0 + (l >> 4) * 4;
    #pragma unroll
    for (int jt = 0; jt < 8; ++jt) {
        int col = jt * 16 + (l & 15);
        float bias = b[col];
        #pragma unroll
        for (int r = 0; r < 4; ++r) {
            int row = rbase + r;
            if (row < NN) {
                float v = fmaxf(acc[jt][r] + bias, 0.f);
                h1f[(size_t)row * HID + col] = v;
                h1b[(size_t)row * HID + col] = f2bf(v);
                unsigned q8 = (unsigned)__builtin_amdgcn_cvt_pk_fp8_f32(v, 0.f, 0, false) & 0xFFu;
                h1q[(size_t)row * HID + col] = (unsigned char)q8;
            }
        }
    }
}

__global__ __launch_bounds__(256) void mfma2_kernel(const unsigned short* __restrict__ h1b,
                                                    const unsigned short* __restrict__ m2b,
                                                    const unsigned short* __restrict__ Wp,
                                                    const float* __restrict__ b,
                                                    const float* __restrict__ Wout,
                                                    const float* __restrict__ bout,
                                                    float* __restrict__ h2f,
                                                    float* __restrict__ out) {
    int t = threadIdx.x, w = t >> 6, l = t & 63;
    int row0 = blockIdx.x * 64 + w * 16;
    int arow = row0 + (l & 15); if (arow > NN - 1) arow = NN - 1;
    int kcol = (l >> 4) * 8;
    f32x4 acc[8];
    #pragma unroll
    for (int jt = 0; jt < 8; ++jt) { acc[jt][0] = 0.f; acc[jt][1] = 0.f; acc[jt][2] = 0.f; acc[jt][3] = 0.f; }
    #pragma unroll
    for (int ks = 0; ks < 8; ++ks) {
        const unsigned short* A = (ks < 4) ? h1b : m2b;
        int c = (ks & 3) * 32 + kcol;
        bf16x8 a = *reinterpret_cast<const bf16x8*>(A + (size_t)arow * HID + c);
        #pragma unroll
        for (int jt = 0; jt < 8; ++jt) {
            bf16x8 bb = *reinterpret_cast<const bf16x8*>(Wp + ((size_t)(jt * 8 + ks) * 64 + l) * 8);
            acc[jt] = __builtin_amdgcn_mfma_f32_16x16x32_bf16(a, bb, acc[jt], 0, 0, 0);
        }
    }
    int rbase = row0 + (l >> 4) * 4;
    float hs0 = 0.f, hs1 = 0.f, hs2 = 0.f, hs3 = 0.f;
    #pragma unroll
    for (int jt = 0; jt < 8; ++jt) {
        int col = jt * 16 + (l & 15);
        float bias = b[col];
        float wo = Wout[col];
        #pragma unroll
        for (int r = 0; r < 4; ++r) {
            int row = rbase + r;
            float v = acc[jt][r] + bias;
            if (row < NN) h2f[(size_t)row * HID + col] = v;
            if (r == 0) hs0 += v * wo;
            else if (r == 1) hs1 += v * wo;
            else if (r == 2) hs2 += v * wo;
            else hs3 += v * wo;
        }
    }
    #pragma unroll
    for (int o = 1; o < 16; o <<= 1) {
        hs0 += __shfl_xor(hs0, o);
        hs1 += __shfl_xor(hs1, o);
        hs2 += __shfl_xor(hs2, o);
        hs3 += __shfl_xor(hs3, o);
    }
    if ((l & 15) == 0) {
        float bo = bout[0];
        if (rbase + 0 < NN) out[rbase + 0] = hs0 + bo;
        if (rbase + 1 < NN) out[rbase + 1] = hs1 + bo;
        if (rbase + 2 < NN) out[rbase + 2] = hs2 + bo;
        if (rbase + 3 < NN) out[rbase + 3] = hs3 + bo;
    }
}

// ===================== fp32 CSR fallback (round-2) =====================

__global__ __launch_bounds__(256) void zero_int_kernel(int4* __restrict__ p, int n4) {
    int i = blockIdx.x * 256 + threadIdx.x;
    if (i < n4) p[i] = make_int4(0, 0, 0, 0);
}

__global__ __launch_bounds__(256) void hist_kernel(const int* __restrict__ dst,
                                                   int* __restrict__ cnt) {
    int e = blockIdx.x * 256 + threadIdx.x;
    if (e < NE) atomicAdd(&cnt[dst[e]], 1);
}

__global__ __launch_bounds__(256) void scanA_kernel(const int* __restrict__ cnt,
                                                    int* __restrict__ bsums) {
    int b = blockIdx.x, t = threadIdx.x;
    int base = b * SCAN_CHUNK + t * 4;
    int s = 0;
    #pragma unroll
    for (int k = 0; k < 4; ++k) { int i = base + k; if (i < NN) s += cnt[i]; }
    #pragma unroll
    for (int o = 32; o > 0; o >>= 1) s += __shfl_down(s, o);
    __shared__ int wsum[4];
    if ((t & 63) == 0) wsum[t >> 6] = s;
    __syncthreads();
    if (t == 0) bsums[b] = wsum[0] + wsum[1] + wsum[2] + wsum[3];
}

__global__ void scanB_kernel(int* __restrict__ bsums) {
    int acc = 0;
    for (int i = 0; i < NSB; ++i) { int v = bsums[i]; bsums[i] = acc; acc += v; }
}

__global__ __launch_bounds__(256) void scanC_kernel(const int* __restrict__ cnt,
                                                    const int* __restrict__ bsums,
                                                    int* __restrict__ off,
                                                    int* __restrict__ cur) {
    int b = blockIdx.x, t = threadIdx.x;
    int lane = t & 63, w = t >> 6;
    int base = b * SCAN_CHUNK + t * 4;
    int v[4]; int s = 0;
    #pragma unroll
    for (int k = 0; k < 4; ++k) {
        int i = base + k;
        v[k] = (i < NN) ? cnt[i] : 0;
        s += v[k];
    }
    int inc = s;
    #pragma unroll
    for (int o = 1; o < 64; o <<= 1) {
        int xv = __shfl_up(inc, o);
        if (lane >= o) inc += xv;
    }
    __shared__ int wsum[4];
    if (lane == 63) wsum[w] = inc;
    __syncthreads();
    int wbase = 0;
    for (int i = 0; i < w; ++i) wbase += wsum[i];
    int ex = bsums[b] + wbase + (inc - s);
    #pragma unroll
    for (int k = 0; k < 4; ++k) {
        int i = base + k;
        if (i < NN) { off[i] = ex; cur[i] = ex; }
        ex += v[k];
    }
}

__global__ __launch_bounds__(256) void fill_kernel(const int* __restrict__ src,
                                                   const int* __restrict__ dst,
                                                   int* __restrict__ cur,
                                                   int* __restrict__ srcs) {
    int e = blockIdx.x * 256 + threadIdx.x;
    if (e < NE) {
        int p = atomicAdd(&cur[dst[e]], 1);
        srcs[p] = src[e];
    }
}

__global__ __launch_bounds__(256) void agg1f_kernel(const float* __restrict__ x,
                                                    const int* __restrict__ srcs,
                                                    const int* __restrict__ off,
                                                    const int* __restrict__ cnt,
                                                    float* __restrict__ mean1) {
    int t = threadIdx.x;
    int n = blockIdx.x * 4 + (t >> 6);
    int d = t & 63;
    int s0 = off[n], deg = cnt[n];
    float acc = 0.f;
    for (int e = 0; e < deg; ++e) acc += x[(size_t)srcs[s0 + e] * IND + d];
    mean1[(size_t)n * HID + d] = acc / fmaxf((float)deg, 1.f);
}

__global__ __launch_bounds__(256) void agg2f_kernel(const float* __restrict__ h1,
                                                    const int* __restrict__ srcs,
                                                    const int* __restrict__ off,
                                                    const int* __restrict__ cnt,
                                                    float* __restrict__ mean2) {
    int t = threadIdx.x;
    int n = blockIdx.x * 2 + (t >> 7);
    int d = t & 127;
    int s0 = off[n], deg = cnt[n];
    float acc = 0.f;
    for (int e = 0; e < deg; ++e) acc += h1[(size_t)srcs[s0 + e] * HID + d];
    mean2[(size_t)n * HID + d] = acc / fmaxf((float)deg, 1.f);
}

__global__ __launch_bounds__(256) void gemm1f_kernel(const float* __restrict__ x,
                                                     const float* __restrict__ Wl,
                                                     const float* __restrict__ Wr,
                                                     const float* __restrict__ b,
                                                     float* __restrict__ h1) {
    __shared__ float in[16][128];
    int t = threadIdx.x;
    int node0 = blockIdx.x * 16;
    for (int idx = t; idx < 16 * 128; idx += 256) {
        int r = idx >> 7, c = idx & 127;
        in[r][c] = (c < IND) ? x[(size_t)(node0 + r) * IND + c]
                             : h1[(size_t)(node0 + r) * HID + (c - IND)];
    }
    __syncthreads();
    int j = t & 127, g = t >> 7;
    float acc[8];
    float bj = b[j];
    #pragma unroll
    for (int q = 0; q < 8; ++q) acc[q] = bj;
    for (int k = 0; k < 128; ++k) {
        float wv = (k < IND) ? Wr[k * HID + j] : Wl[(k - IND) * HID + j];
        #pragma unroll
        for (int q = 0; q < 8; ++q) acc[q] += in[g * 8 + q][k] * wv;
    }
    #pragma unroll
    for (int q = 0; q < 8; ++q)
        h1[(size_t)(node0 + g * 8 + q) * HID + j] = fmaxf(acc[q], 0.f);
}

__global__ __launch_bounds__(256) void gemm2f_kernel(const float* __restrict__ h1,
                                                     const float* __restrict__ Wl,
                                                     const float* __restrict__ Wr,
                                                     const float* __restrict__ b,
                                                     const float* __restrict__ Wout,
                                                     const float* __restrict__ bout,
                                                     float* __restrict__ h2,
                                                     float* __restrict__ out) {
    __shared__ float in[16][256];
    __shared__ float part[4][8];
    int t = threadIdx.x;
    int node0 = blockIdx.x * 16;
    for (int idx = t; idx < 16 * 256; idx += 256) {
        int r = idx >> 8, c = idx & 255;
        in[r][c] = (c < HID) ? h1[(size_t)(node0 + r) * HID + c]
                             : h2[(size_t)(node0 + r) * HID + (c - HID)];
    }
    __syncthreads();
    int j = t & 127, g = t >> 7, lane = t & 63, w = t >> 6;
    float acc[8];
    float bj = b[j];
    #pragma unroll
    for (int q = 0; q < 8; ++q) acc[q] = bj;
    for (int k = 0; k < 256; ++k) {
        float wv = (k < HID) ? Wr[k * HID + j] : Wl[(k - HID) * HID + j];
        #pragma unroll
        for (int q = 0; q < 8; ++q) acc[q] += in[g * 8 + q][k] * wv;
    }
    float wo = Wout[j];
    #pragma unroll
    for (int q = 0; q < 8; ++q)
        h2[(size_t)(node0 + g * 8 + q) * HID + j] = acc[q];
    #pragma unroll
    for (int q = 0; q < 8; ++q) {
        float v = acc[q] * wo;
        #pragma unroll
        for (int o = 32; o > 0; o >>= 1) v += __shfl_down(v, o);
        if (lane == 0) part[w][q] = v;
    }
    __syncthreads();
    if (t < 16) {
        int gg = t >> 3, q = t & 7;
        out[node0 + t] = part[2 * gg][q] + part[2 * gg + 1][q] + bout[0];
    }
}

// ============================ launch ============================

extern "C" void kernel_launch(void* const* d_in, const int* in_sizes, int n_in,
                              void* d_out, int out_size, void* d_ws, size_t ws_size,
                              hipStream_t stream) {
    const float* x    = (const float*)d_in[0];
    const int*   eidx = (const int*)d_in[1];
    const int*   src  = eidx;
    const int*   dst  = eidx + NE;
    const float* Wl1  = (const float*)d_in[2];
    const float* Wr1  = (const float*)d_in[3];
    const float* b1   = (const float*)d_in[4];
    const float* Wl2  = (const float*)d_in[5];
    const float* Wr2  = (const float*)d_in[6];
    const float* b2   = (const float*)d_in[7];
    const float* Wout = (const float*)d_in[8];
    const float* bout = (const float*)d_in[9];

    float* out = (float*)d_out;
    float* h1f = out + NN;
    float* h2f = h1f + (size_t)NN * HID;

    // ---- workspace layout (~92 MB) ----
    char* p = (char*)d_ws;
    int* cnt        = (int*)p;            p += (size_t)NN * 4;
    int* off        = (int*)p;            p += (size_t)NN * 4;
    int* bktcur     = (int*)p;            p += 512 * 4;
    unsigned* bins  = (unsigned*)p;       p += (size_t)NBKT2 * CAP * 4; // 7.8MB (becomes srcs)
    unsigned char* xq  = (unsigned char*)p;   p += (size_t)NN * IND;    // 6.4MB
    unsigned short* m1b = (unsigned short*)p; p += (size_t)NN * IND * 2; // 12.8MB
    unsigned short* h1b = (unsigned short*)p; p += (size_t)NN * HID * 2; // 25.6MB
    unsigned char* h1q  = (unsigned char*)p;  p += (size_t)NN * HID;     // 12.8MB
    unsigned short* m2b = (unsigned short*)p; p += (size_t)NN * HID * 2; // 25.6MB
    unsigned short* Wp1 = (unsigned short*)p; p += 8 * 4 * 64 * 8 * 2;   // 32KB
    unsigned short* Wp2 = (unsigned short*)p; p += 8 * 8 * 64 * 8 * 2;   // 64KB
    const size_t need_v3 = (size_t)(p - (char*)d_ws);
    const size_t need_csr = ((size_t)3 * NN + 128 + NE) * sizeof(int);

    if (ws_size >= need_v3) {
        prep_kernel<<<CVT_BLKS + PW1_BLKS + PW2_BLKS + 1, 256, 0, stream>>>(
            (const float4*)x, (unsigned*)xq, Wr1, Wl1, Wp1, Wr2, Wl2, Wp2, bktcur);
        binA_kernel<<<NBLK_E, 512, 0, stream>>>(src, dst, bktcur, bins);
        binB_kernel<<<NBKT2, 512, 0, stream>>>(bktcur, bins, cnt, off);
        agg1_kernel<<<NN / 4, 256, 0, stream>>>(xq, (const int*)bins, off, cnt, m1b);
        mfma1_kernel<<<(NN + 63) / 64, 256, 0, stream>>>(x, m1b, Wp1, b1, h1f, h1b, h1q);
        agg2_kernel<<<NN / 4, 256, 0, stream>>>(h1q, (const int*)bins, off, cnt, m2b);
        mfma2_kernel<<<(NN + 63) / 64, 256, 0, stream>>>(h1b, m2b, Wp2, b2, Wout, bout, h2f, out);
    } else if (ws_size >= need_csr) {
        int* cntF   = (int*)d_ws;
        int* offF   = cntF + NN;
        int* curF   = offF + NN;
        int* bsums  = curF + NN;
        int* srcsF  = bsums + 128;
        zero_int_kernel<<<(NN / 4 + 255) / 256, 256, 0, stream>>>((int4*)cntF, NN / 4);
        hist_kernel<<<(NE + 255) / 256, 256, 0, stream>>>(dst, cntF);
        scanA_kernel<<<NSB, 256, 0, stream>>>(cntF, bsums);
        scanB_kernel<<<1, 1, 0, stream>>>(bsums);
        scanC_kernel<<<NSB, 256, 0, stream>>>(cntF, bsums, offF, curF);
        fill_kernel<<<(NE + 255) / 256, 256, 0, stream>>>(src, dst, curF, srcsF);
        agg1f_kernel<<<NN / 4, 256, 0, stream>>>(x, srcsF, offF, cntF, h1f);
        gemm1f_kernel<<<NN / 16, 256, 0, stream>>>(x, Wl1, Wr1, b1, h1f);
        agg2f_kernel<<<NN / 2, 256, 0, stream>>>(h1f, srcsF, offF, cntF, h2f);
        gemm2f_kernel<<<NN / 16, 256, 0, stream>>>(h1f, Wl2, Wr2, b2, Wout, bout, h2f, out);
    }
}